// Round 12
// baseline (219.244 us; speedup 1.0000x reference)
//
#include <hip/hip_runtime.h>
#include <hip/hip_bf16.h>
#include <cstdint>

typedef __bf16 bf16_t;
typedef __bf16 bf16x4 __attribute__((ext_vector_type(4)));
typedef __bf16 bf16x8 __attribute__((ext_vector_type(8)));
typedef float floatx4 __attribute__((ext_vector_type(4)));
typedef float floatx16 __attribute__((ext_vector_type(16)));
typedef unsigned int u32x4 __attribute__((ext_vector_type(4)));

#define NB 4
#define NH 12
#define SEQ 2048
#define DM 768
#define LOG2E 1.44269504088896340736f

// async global->LDS, 16B per lane; LDS dest is wave-uniform base + lane*16
__device__ __forceinline__ void gload_lds16(const bf16_t* g, bf16_t* l) {
  auto gp = reinterpret_cast<const __attribute__((address_space(1))) uint32_t*>(
      reinterpret_cast<uintptr_t>(g));
  auto lp = reinterpret_cast<__attribute__((address_space(3))) uint32_t*>(
      reinterpret_cast<uintptr_t>(l));
  __builtin_amdgcn_global_load_lds(gp, lp, 16, 0, 0);
}

// pack two f32 -> one dword of 2 bf16 (lo = a, hi = b)
__device__ __forceinline__ unsigned int pack2(float a, float b) {
  bf16_t x = (bf16_t)a, y = (bf16_t)b;
  unsigned short ux = __builtin_bit_cast(unsigned short, x);
  unsigned short uy = __builtin_bit_cast(unsigned short, y);
  return (unsigned int)ux | ((unsigned int)uy << 16);
}

// ---------------------------------------------------------------- fused prep
__global__ __launch_bounds__(256) void prep_kernel(
    const float* __restrict__ x, bf16_t* __restrict__ xb,
    const float* __restrict__ wqkv, bf16_t* __restrict__ wqkvT,
    const float* __restrict__ wproj, bf16_t* __restrict__ wprojT) {
  const int bid = blockIdx.x;
  const int tid = threadIdx.x;
  if (bid < 6144) {
    int i = (bid * 256 + tid) * 4;
    float4 v = *(const float4*)(x + i);
    bf16x4 hh;
    hh[0] = (bf16_t)v.x; hh[1] = (bf16_t)v.y; hh[2] = (bf16_t)v.z; hh[3] = (bf16_t)v.w;
    *(bf16x4*)(xb + i) = hh;
    return;
  }
  const float* in;
  bf16_t* out;
  int N, nb, kb;
  if (bid < 7872) {
    int t = bid - 6144;
    in = wqkv; out = wqkvT; N = 2304;
    nb = (t % 72) * 32; kb = (t / 72) * 32;
  } else {
    int t = bid - 7872;
    in = wproj; out = wprojT; N = 768;
    nb = (t % 24) * 32; kb = (t / 24) * 32;
  }
  const int K = 768;
  __shared__ float tile[32][33];
  int tx = tid & 31, ty = tid >> 5;
#pragma unroll
  for (int r = ty; r < 32; r += 8)
    tile[r][tx] = in[(size_t)(kb + r) * N + nb + tx];
  __syncthreads();
#pragma unroll
  for (int r = ty; r < 32; r += 8)
    out[(size_t)(nb + r) * K + kb + tx] = (bf16_t)tile[tx][r];
}

// ---------------------------------------------------------------- QKV GEMM
// Single-buffer m97 (R5 proven; R11's triple-buffer was NULL — LDS cost offset
// prefetch gain). NEW: V blocks (which==2) write C through an LDS transpose
// (aliasing the dead As/Bs, [128][136] pad -> 16B-aligned row reads) straight
// to Vt[bh][hd][s], coalesced 128B/thread — the vtrans kernel is deleted.
__global__ __launch_bounds__(256) void gemm_qkv_kernel(
    const bf16_t* __restrict__ A, const bf16_t* __restrict__ BT,
    const float* __restrict__ bias,
    bf16_t* __restrict__ Qo, bf16_t* __restrict__ Ko, bf16_t* __restrict__ Vto) {
  const int K = 768;
  __shared__ __align__(16) bf16_t smem[128 * 136];  // 34816 B; As/Bs live in front
  bf16_t* As = smem;            // [128][32]
  bf16_t* Bs = smem + 4096;     // [128][32]
  const int m0 = blockIdx.x * 128, n0 = blockIdx.y * 128;
  const int tid = threadIdx.x;
  const int w = tid >> 6, lane = tid & 63, quad = lane >> 4, l16 = lane & 15;
  const int wm = w >> 1, wn = w & 1;
  const int ldrow = w * 32;
  const int grow = lane >> 2;
  const int gcol = (lane & 3) * 8;

  floatx4 acc[4][4];
#pragma unroll
  for (int mt = 0; mt < 4; mt++)
#pragma unroll
    for (int nt = 0; nt < 4; nt++) acc[mt][nt] = (floatx4)(0.f);

  const bf16_t* ga0 = A + (size_t)(m0 + ldrow) * K;
  const bf16_t* gb0 = BT + (size_t)(n0 + ldrow) * K;

  for (int k0 = 0; k0 < K; k0 += 32) {
    __syncthreads();
    gload_lds16(ga0 + (size_t)grow * K + k0 + gcol,        &As[ldrow * 32]);
    gload_lds16(ga0 + (size_t)(grow + 16) * K + k0 + gcol, &As[(ldrow + 16) * 32]);
    gload_lds16(gb0 + (size_t)grow * K + k0 + gcol,        &Bs[ldrow * 32]);
    gload_lds16(gb0 + (size_t)(grow + 16) * K + k0 + gcol, &Bs[(ldrow + 16) * 32]);
    __syncthreads();
    bf16x8 af[4], bfr[4];
#pragma unroll
    for (int mt = 0; mt < 4; mt++)
      af[mt] = *(const bf16x8*)&As[(wm * 64 + mt * 16 + l16) * 32 + quad * 8];
#pragma unroll
    for (int nt = 0; nt < 4; nt++)
      bfr[nt] = *(const bf16x8*)&Bs[(wn * 64 + nt * 16 + l16) * 32 + quad * 8];
#pragma unroll
    for (int mt = 0; mt < 4; mt++)
#pragma unroll
      for (int nt = 0; nt < 4; nt++)
        acc[mt][nt] = __builtin_amdgcn_mfma_f32_16x16x32_bf16(af[mt], bfr[nt], acc[mt][nt], 0, 0, 0);
  }

  const int which = n0 / 768;
  const int rem0 = n0 % 768;
  if (which < 2) {
    bf16_t* dst = which == 0 ? Qo : Ko;
    const float qscale = which == 0 ? (0.125f * LOG2E) : 1.0f;
#pragma unroll
    for (int nt = 0; nt < 4; nt++) {
      const int cc = wn * 64 + nt * 16 + l16;
      const int rem = rem0 + cc;
      const int h = rem >> 6, hd = rem & 63;
      const float bv = bias[n0 + cc];
#pragma unroll
      for (int mt = 0; mt < 4; mt++)
#pragma unroll
        for (int r = 0; r < 4; r++) {
          const int gr = m0 + wm * 64 + mt * 16 + quad * 4 + r;
          const int bb = gr >> 11, s = gr & 2047;
          const float val = (acc[mt][nt][r] + bv) * qscale;
          dst[((size_t)((bb * NH + h) * SEQ + s)) * 64 + hd] = (bf16_t)val;
        }
    }
  } else {
    // V: transpose through LDS (smem reused — As/Bs dead after this barrier)
    __syncthreads();
#pragma unroll
    for (int nt = 0; nt < 4; nt++) {
      const int c = wn * 64 + nt * 16 + l16;
      const float bv = bias[n0 + c];
#pragma unroll
      for (int mt = 0; mt < 4; mt++)
#pragma unroll
        for (int r = 0; r < 4; r++) {
          const int grl = wm * 64 + mt * 16 + quad * 4 + r;
          smem[c * 136 + grl] = (bf16_t)(acc[mt][nt][r] + bv);
        }
    }
    __syncthreads();
    const int c = tid >> 1, half = tid & 1;
    const int rem = rem0 + c;
    const int h = rem >> 6, hd = rem & 63;
    const int bb = m0 >> 11;
    const int s0 = (m0 & 2047) + half * 64;
    bf16_t* dstp = Vto + (((size_t)(bb * NH + h) * 64 + hd) << 11) + s0;
#pragma unroll
    for (int j = 0; j < 8; j++)
      *(bf16x8*)(dstp + j * 8) = *(const bf16x8*)&smem[c * 136 + half * 64 + j * 8];
  }
}

// ---------------------------------------------------------------- flash attention
// Same inner math as R9 (swapped-QK^T 32x32, pre-swizzled src + XOR reads,
// T13 defer-max, ones-MFMA l-sum). Restructured to 2-WAVE blocks (128 thr),
// 64 q-rows/block, grid (48,32) = 1536 blocks: smaller barrier domains and
// ~5 blocks/CU (double-buffer 32KB; grid was the 3/CU cap before, R10 showed
// bigger blocks regress). R6's 2-barrier schedule (proven correct), vmcnt(8).
// Both waves have ntmax = qt+1 tiles -> no idle-wave guard.
__global__ __launch_bounds__(128, 3) void attn_kernel(
    const bf16_t* __restrict__ Q, const bf16_t* __restrict__ Kg,
    const bf16_t* __restrict__ Vt, bf16_t* __restrict__ Out) {
  __shared__ __align__(16) bf16_t Ks[2][64 * 64];  // 8KB per buf
  __shared__ __align__(16) bf16_t Vs[2][64 * 64];  // 8KB per buf (V^T layout)
  const int tid = threadIdx.x;                     // 0..127
  const int w = tid >> 6, lane = tid & 63;
  const int l31 = lane & 31, hi = lane >> 5;
  const int bh = blockIdx.x;
  const int b = bh / NH, h = bh % NH;
  const int qt = (int)(gridDim.y - 1) - (int)blockIdx.y;  // heaviest first, 0..31
  const int r0 = qt * 64 + w * 32;
  const int qrow = r0 + l31;
  const bf16_t* Qp = Q + (size_t)bh * SEQ * 64;
  const bf16_t* Kp = Kg + (size_t)bh * SEQ * 64;
  const bf16_t* Vp = Vt + (size_t)bh * 64 * SEQ;

  bf16x8 qf[4];
#pragma unroll
  for (int kc = 0; kc < 4; kc++)
    qf[kc] = *(const bf16x8*)&Qp[(size_t)qrow * 64 + kc * 16 + hi * 8];

  bf16x8 ones;
#pragma unroll
  for (int j = 0; j < 8; j++) ones[j] = (bf16_t)1.0f;

  float m_i = -1e30f;
  floatx16 accT[2];
  accT[0] = (floatx16)(0.f);
  accT[1] = (floatx16)(0.f);
  floatx16 zl = (floatx16)(0.f);

  const int ntmax = qt + 1;  // same for both waves

  // staging: 4 rounds x 128 threads x 16B = 8KB per buffer
  int srow[4], scolb[4];
#pragma unroll
  for (int r = 0; r < 4; r++) {
    int off = r * 2048 + tid * 16;
    int row = off >> 7;
    srow[r] = row;
    scolb[r] = (off & 127) ^ ((row & 7) << 4);
  }

  auto stage = [&](int buf, int kt) {
    const int kbase = kt * 64;
#pragma unroll
    for (int r = 0; r < 4; r++) {
      gload_lds16(Kp + (size_t)(kbase + srow[r]) * 64 + (scolb[r] >> 1),
                  &Ks[buf][r * 1024 + w * 512]);
      gload_lds16(Vp + (size_t)srow[r] * SEQ + kbase + (scolb[r] >> 1),
                  &Vs[buf][r * 1024 + w * 512]);
    }
  };

  const int swz = (l31 & 7) << 4;

  stage(0, 0);

  int cur = 0;
  for (int kt = 0; kt < ntmax; kt++) {
    if (kt + 1 < ntmax) {
      stage(cur ^ 1, kt + 1);
      asm volatile("s_waitcnt vmcnt(8)" ::: "memory");  // buf[cur] landed
    } else {
      asm volatile("s_waitcnt vmcnt(0)" ::: "memory");
    }
    __builtin_amdgcn_s_barrier();  // (1) stage of buf[cur] visible

    {
      const int kbase = kt * 64;
      const bf16_t* Kb = Ks[cur];
      const bf16_t* Vb = Vs[cur];
      floatx16 st[2];
#pragma unroll
      for (int kt2 = 0; kt2 < 2; kt2++) {
        const int row = kt2 * 32 + l31;
        floatx16 z = (floatx16)(0.f);
#pragma unroll
        for (int kc = 0; kc < 4; kc++) {
          bf16x8 kfr = *(const bf16x8*)&Kb[row * 64 + (((kc * 32 + hi * 16) ^ swz) >> 1)];
          z = __builtin_amdgcn_mfma_f32_32x32x16_bf16(kfr, qf[kc], z, 0, 0, 0);
        }
        st[kt2] = z;
      }
      if (kt == ntmax - 1) {  // causal mask, last tile only
#pragma unroll
        for (int kt2 = 0; kt2 < 2; kt2++)
#pragma unroll
          for (int r = 0; r < 16; r++) {
            int key = kbase + kt2 * 32 + (r & 3) + 8 * (r >> 2) + 4 * hi;
            if (key > qrow) st[kt2][r] = -1e30f;
          }
      }
      float mloc = -1e30f;
#pragma unroll
      for (int kt2 = 0; kt2 < 2; kt2++)
#pragma unroll
        for (int r = 0; r < 16; r++) mloc = fmaxf(mloc, st[kt2][r]);
      mloc = fmaxf(mloc, __shfl_xor(mloc, 32));
      if (!__all((int)(mloc - m_i <= 8.f))) {
        const float mnew = fmaxf(m_i, mloc);
        const float al = __builtin_amdgcn_exp2f(m_i - mnew);
        m_i = mnew;
#pragma unroll
        for (int r = 0; r < 16; r++) zl[r] *= al;
#pragma unroll
        for (int dt = 0; dt < 2; dt++)
#pragma unroll
          for (int r = 0; r < 16; r++) accT[dt][r] *= al;
      }
#pragma unroll
      for (int kt2 = 0; kt2 < 2; kt2++)
#pragma unroll
        for (int r = 0; r < 16; r++)
          st[kt2][r] = __builtin_amdgcn_exp2f(st[kt2][r] - m_i);
#pragma unroll
      for (int kt2 = 0; kt2 < 2; kt2++) {
        unsigned int wds[8];
#pragma unroll
        for (int j = 0; j < 8; j++) wds[j] = pack2(st[kt2][2 * j], st[kt2][2 * j + 1]);
        unsigned int x0 = (unsigned int)__shfl_xor((int)(hi ? wds[0] : wds[2]), 32);
        unsigned int x1 = (unsigned int)__shfl_xor((int)(hi ? wds[1] : wds[3]), 32);
        unsigned int x2 = (unsigned int)__shfl_xor((int)(hi ? wds[4] : wds[6]), 32);
        unsigned int x3 = (unsigned int)__shfl_xor((int)(hi ? wds[5] : wds[7]), 32);
        u32x4 f0 = hi ? (u32x4){x0, x1, wds[2], wds[3]} : (u32x4){wds[0], wds[1], x0, x1};
        u32x4 f1 = hi ? (u32x4){x2, x3, wds[6], wds[7]} : (u32x4){wds[4], wds[5], x2, x3};
        bf16x8 pf0 = __builtin_bit_cast(bf16x8, f0);
        bf16x8 pf1 = __builtin_bit_cast(bf16x8, f1);
        zl = __builtin_amdgcn_mfma_f32_32x32x16_bf16(ones, pf0, zl, 0, 0, 0);
        zl = __builtin_amdgcn_mfma_f32_32x32x16_bf16(ones, pf1, zl, 0, 0, 0);
#pragma unroll
        for (int dt = 0; dt < 2; dt++) {
          const int vrow = dt * 32 + l31;
          bf16x8 v0 = *(const bf16x8*)&Vb[vrow * 64 + (((kt2 * 64 + hi * 16) ^ swz) >> 1)];
          bf16x8 v1 = *(const bf16x8*)&Vb[vrow * 64 + (((kt2 * 64 + 32 + hi * 16) ^ swz) >> 1)];
          accT[dt] = __builtin_amdgcn_mfma_f32_32x32x16_bf16(v0, pf0, accT[dt], 0, 0, 0);
          accT[dt] = __builtin_amdgcn_mfma_f32_32x32x16_bf16(v1, pf1, accT[dt], 0, 0, 0);
        }
      }
    }
    __builtin_amdgcn_s_barrier();  // (2) buf[cur] reads done before re-stage
    cur ^= 1;
  }

  const float inv_l = 1.0f / zl[0];
#pragma unroll
  for (int dt = 0; dt < 2; dt++)
#pragma unroll
    for (int g = 0; g < 4; g++) {
      bf16x4 o;
#pragma unroll
      for (int j = 0; j < 4; j++) o[j] = (bf16_t)(accT[dt][4 * g + j] * inv_l);
      int d = dt * 32 + 8 * g + 4 * hi;
      *(bf16x4*)&Out[((size_t)(b * SEQ + qrow)) * DM + h * 64 + d] = o;
    }
}

// ---------------------------------------------------------------- out-proj GEMM (m97 single-buffer)
__global__ __launch_bounds__(256) void gemm_proj_kernel(
    const bf16_t* __restrict__ A, const bf16_t* __restrict__ BT,
    const float* __restrict__ bias, float* __restrict__ out) {
  const int K = 768;
  __shared__ __align__(16) bf16_t As[128][32];
  __shared__ __align__(16) bf16_t Bs[128][32];
  const int m0 = blockIdx.x * 128, n0 = blockIdx.y * 128;
  const int tid = threadIdx.x;
  const int w = tid >> 6, lane = tid & 63, quad = lane >> 4, l16 = lane & 15;
  const int wm = w >> 1, wn = w & 1;
  const int ldrow = w * 32;
  const int grow = lane >> 2;
  const int gcol = (lane & 3) * 8;

  floatx4 acc[4][4];
#pragma unroll
  for (int mt = 0; mt < 4; mt++)
#pragma unroll
    for (int nt = 0; nt < 4; nt++) acc[mt][nt] = (floatx4)(0.f);

  const bf16_t* ga0 = A + (size_t)(m0 + ldrow) * K;
  const bf16_t* gb0 = BT + (size_t)(n0 + ldrow) * K;

  for (int k0 = 0; k0 < K; k0 += 32) {
    __syncthreads();
    gload_lds16(ga0 + (size_t)grow * K + k0 + gcol,        &As[ldrow][0]);
    gload_lds16(ga0 + (size_t)(grow + 16) * K + k0 + gcol, &As[ldrow + 16][0]);
    gload_lds16(gb0 + (size_t)grow * K + k0 + gcol,        &Bs[ldrow][0]);
    gload_lds16(gb0 + (size_t)(grow + 16) * K + k0 + gcol, &Bs[ldrow + 16][0]);
    __syncthreads();
    bf16x8 af[4], bfr[4];
#pragma unroll
    for (int mt = 0; mt < 4; mt++)
      af[mt] = *(const bf16x8*)&As[wm * 64 + mt * 16 + l16][quad * 8];
#pragma unroll
    for (int nt = 0; nt < 4; nt++)
      bfr[nt] = *(const bf16x8*)&Bs[wn * 64 + nt * 16 + l16][quad * 8];
#pragma unroll
    for (int mt = 0; mt < 4; mt++)
#pragma unroll
      for (int nt = 0; nt < 4; nt++)
        acc[mt][nt] = __builtin_amdgcn_mfma_f32_16x16x32_bf16(af[mt], bfr[nt], acc[mt][nt], 0, 0, 0);
  }

#pragma unroll
  for (int nt = 0; nt < 4; nt++) {
    const int gc = n0 + wn * 64 + nt * 16 + l16;
    const float bv = bias[gc];
#pragma unroll
    for (int mt = 0; mt < 4; mt++)
#pragma unroll
      for (int r = 0; r < 4; r++) {
        const int gr = m0 + wm * 64 + mt * 16 + quad * 4 + r;
        out[(size_t)gr * 768 + gc] = acc[mt][nt][r] + bv;
      }
  }
}

// ---------------------------------------------------------------- launch
extern "C" void kernel_launch(void* const* d_in, const int* in_sizes, int n_in,
                              void* d_out, int out_size, void* d_ws, size_t ws_size,
                              hipStream_t stream) {
  const float* x      = (const float*)d_in[0];
  const float* w_qkv  = (const float*)d_in[1];
  const float* b_qkv  = (const float*)d_in[2];
  const float* w_proj = (const float*)d_in[3];
  const float* b_proj = (const float*)d_in[4];
  float* out = (float*)d_out;
  char* ws = (char*)d_ws;

  // workspace layout (all 16B-aligned), total 67,633,152 B
  bf16_t* xb     = (bf16_t*)(ws + 0);         // 8192*768  bf16
  bf16_t* wqkvT  = (bf16_t*)(ws + 12582912);  // 2304*768  bf16
  bf16_t* wprojT = (bf16_t*)(ws + 16121856);  //  768*768  bf16
  bf16_t* q      = (bf16_t*)(ws + 17301504);  // [4][12][2048][64] bf16
  bf16_t* k      = (bf16_t*)(ws + 29884416);
  bf16_t* vt     = (bf16_t*)(ws + 42467328);  // [4][12][64][2048] bf16 (old v slot; V written transposed by gemm_qkv)
  bf16_t* ao     = (bf16_t*)(ws + 55050240);  // [8192][768] bf16

  prep_kernel<<<8448, 256, 0, stream>>>(x, xb, w_qkv, wqkvT, w_proj, wprojT);
  gemm_qkv_kernel<<<dim3(64, 18), 256, 0, stream>>>(xb, wqkvT, b_qkv, q, k, vt);
  attn_kernel<<<dim3(48, 32), 128, 0, stream>>>(q, k, vt, ao);
  gemm_proj_kernel<<<dim3(64, 6), 256, 0, stream>>>(ao, wprojT, b_proj, out);
}

// Round 13
// 216.813 us; speedup vs baseline: 1.0112x; 1.0112x over previous
//
#include <hip/hip_runtime.h>
#include <hip/hip_bf16.h>
#include <cstdint>

typedef __bf16 bf16_t;
typedef __bf16 bf16x4 __attribute__((ext_vector_type(4)));
typedef __bf16 bf16x8 __attribute__((ext_vector_type(8)));
typedef float floatx4 __attribute__((ext_vector_type(4)));
typedef float floatx16 __attribute__((ext_vector_type(16)));
typedef unsigned int u32x4 __attribute__((ext_vector_type(4)));

#define NB 4
#define NH 12
#define SEQ 2048
#define DM 768
#define LOG2E 1.44269504088896340736f

// async global->LDS, 16B per lane; LDS dest is wave-uniform base + lane*16
__device__ __forceinline__ void gload_lds16(const bf16_t* g, bf16_t* l) {
  auto gp = reinterpret_cast<const __attribute__((address_space(1))) uint32_t*>(
      reinterpret_cast<uintptr_t>(g));
  auto lp = reinterpret_cast<__attribute__((address_space(3))) uint32_t*>(
      reinterpret_cast<uintptr_t>(l));
  __builtin_amdgcn_global_load_lds(gp, lp, 16, 0, 0);
}

// pack two f32 -> one dword of 2 bf16 (lo = a, hi = b)
__device__ __forceinline__ unsigned int pack2(float a, float b) {
  bf16_t x = (bf16_t)a, y = (bf16_t)b;
  unsigned short ux = __builtin_bit_cast(unsigned short, x);
  unsigned short uy = __builtin_bit_cast(unsigned short, y);
  return (unsigned int)ux | ((unsigned int)uy << 16);
}

// ---------------------------------------------------------------- fused prep
__global__ __launch_bounds__(256) void prep_kernel(
    const float* __restrict__ x, bf16_t* __restrict__ xb,
    const float* __restrict__ wqkv, bf16_t* __restrict__ wqkvT,
    const float* __restrict__ wproj, bf16_t* __restrict__ wprojT) {
  const int bid = blockIdx.x;
  const int tid = threadIdx.x;
  if (bid < 6144) {
    int i = (bid * 256 + tid) * 4;
    float4 v = *(const float4*)(x + i);
    bf16x4 hh;
    hh[0] = (bf16_t)v.x; hh[1] = (bf16_t)v.y; hh[2] = (bf16_t)v.z; hh[3] = (bf16_t)v.w;
    *(bf16x4*)(xb + i) = hh;
    return;
  }
  const float* in;
  bf16_t* out;
  int N, nb, kb;
  if (bid < 7872) {
    int t = bid - 6144;
    in = wqkv; out = wqkvT; N = 2304;
    nb = (t % 72) * 32; kb = (t / 72) * 32;
  } else {
    int t = bid - 7872;
    in = wproj; out = wprojT; N = 768;
    nb = (t % 24) * 32; kb = (t / 24) * 32;
  }
  const int K = 768;
  __shared__ float tile[32][33];
  int tx = tid & 31, ty = tid >> 5;
#pragma unroll
  for (int r = ty; r < 32; r += 8)
    tile[r][tx] = in[(size_t)(kb + r) * N + nb + tx];
  __syncthreads();
#pragma unroll
  for (int r = ty; r < 32; r += 8)
    out[(size_t)(nb + r) * K + kb + tx] = (bf16_t)tile[tx][r];
}

// ---------------------------------------------------------------- QKV GEMM (256x256, 8-phase-style)
// BM=BN=256, BK=64, 8 waves (2Mx4N), per-wave out 128x64. LDS 128KB double-buf:
// As/Bs[2][half][128][64]. Per K-tile: 4 phases, each {ds_read subtile (+bf in
// ph0) || stage half-tiles of kt+1 (ph0: A-h0+B-h0, ph1: A-h1+B-h1) -> barrier
// -> lgkmcnt(0)+sched_barrier (rule #18) -> setprio(1) 16 MFMA setprio(0) ->
// barrier}. One vmcnt(0)+barrier per K-tile top (stages there are 2-3 phases
// old). XOR swizzle both sides: stage source col ^= (row&7)<<4 (bytes), reads
// likewise (rule #21). Race-audit: stages into buf nd (iter kt) are >=2
// barriers after all reads of that buf (iter kt-1); readers' lgkmcnt(0)
// precedes their next barrier arrival.
__global__ __launch_bounds__(512, 2) void gemm_qkv_kernel(
    const bf16_t* __restrict__ A, const bf16_t* __restrict__ BT,
    const float* __restrict__ bias,
    bf16_t* __restrict__ Qo, bf16_t* __restrict__ Ko, bf16_t* __restrict__ Vo) {
  const int K = 768;
  const int NKT = 12;  // K / 64
  __shared__ __align__(16) bf16_t As[2][16384];  // [dbuf][half*8192 + row*64 + col]
  __shared__ __align__(16) bf16_t Bs[2][16384];
  const int m0 = blockIdx.x * 256, n0 = blockIdx.y * 256;
  const int tid = threadIdx.x;
  const int w = tid >> 6, lane = tid & 63, quad = lane >> 4, l16 = lane & 15;
  const int wm = w >> 2, wn = w & 3;
  const int swz = (l16 & 7) << 4;  // read-side XOR, bytes (row&7 == l16&7)

  floatx4 acc[8][4];
#pragma unroll
  for (int m = 0; m < 8; m++)
#pragma unroll
    for (int n = 0; n < 4; n++) acc[m][n] = (floatx4)(0.f);

  // staging geometry: per half-tile (128x64 bf16 = 16KB), 512thr x 16B x 2 loads
  int srow[2], scol[2];
#pragma unroll
  for (int j = 0; j < 2; j++) {
    int off = j * 8192 + tid * 16;     // byte offset within half-tile
    int row = off >> 7;
    srow[j] = row;
    scol[j] = (((off & 127) ^ ((row & 7) << 4)) >> 1);  // bf16 units, pre-swizzled
  }

  auto stageA = [&](int d, int h, int kt) {
#pragma unroll
    for (int j = 0; j < 2; j++)
      gload_lds16(A + (size_t)(m0 + h * 128 + srow[j]) * K + kt * 64 + scol[j],
                  &As[d][h * 8192 + j * 4096 + w * 512]);
  };
  auto stageB = [&](int d, int h, int kt) {
#pragma unroll
    for (int j = 0; j < 2; j++)
      gload_lds16(BT + (size_t)(n0 + h * 128 + srow[j]) * K + kt * 64 + scol[j],
                  &Bs[d][h * 8192 + j * 4096 + w * 512]);
  };

  // prologue: K-tile 0 -> dbuf 0 (8 loads/thread)
  stageA(0, 0, 0); stageB(0, 0, 0); stageA(0, 1, 0); stageB(0, 1, 0);

  for (int kt = 0; kt < NKT; kt++) {
    const int d = kt & 1, nd = d ^ 1;
    // tile top: my stages for buf d landed; barrier -> everyone's landed
    asm volatile("s_waitcnt vmcnt(0)" ::: "memory");
    __builtin_amdgcn_s_barrier();

    bf16x8 bf[4][2];
#pragma unroll
    for (int p = 0; p < 4; p++) {
      // ---- ds_read this phase's subtile
      bf16x8 af[2][2];
#pragma unroll
      for (int mi = 0; mi < 2; mi++) {
        const int ri = p * 32 + mi * 16 + l16;  // row within half wm
#pragma unroll
        for (int kk = 0; kk < 2; kk++)
          af[mi][kk] = *(const bf16x8*)&As[d][wm * 8192 + ri * 64 +
                                             (((kk * 64 + quad * 16) ^ swz) >> 1)];
      }
      if (p == 0) {
#pragma unroll
        for (int n = 0; n < 4; n++) {
          const int row = wn * 64 + n * 16 + l16;
          const int h = row >> 7, ri = row & 127;
#pragma unroll
          for (int kk = 0; kk < 2; kk++)
            bf[n][kk] = *(const bf16x8*)&Bs[d][h * 8192 + ri * 64 +
                                              (((kk * 64 + quad * 16) ^ swz) >> 1)];
        }
      }
      // ---- stage next K-tile's half-tiles (ph0: h0, ph1: h1)
      if (p < 2 && kt + 1 < NKT) {
        stageA(nd, p, kt + 1);
        stageB(nd, p, kt + 1);
      }
      __builtin_amdgcn_s_barrier();
      asm volatile("s_waitcnt lgkmcnt(0)" ::: "memory");
      __builtin_amdgcn_sched_barrier(0);  // rule #18: pin MFMA after lgkmcnt
      __builtin_amdgcn_s_setprio(1);
#pragma unroll
      for (int mi = 0; mi < 2; mi++)
#pragma unroll
        for (int n = 0; n < 4; n++)
#pragma unroll
          for (int kk = 0; kk < 2; kk++)
            acc[p * 2 + mi][n] = __builtin_amdgcn_mfma_f32_16x16x32_bf16(
                af[mi][kk], bf[n][kk], acc[p * 2 + mi][n], 0, 0, 0);
      __builtin_amdgcn_s_setprio(0);
      if (p < 3) __builtin_amdgcn_s_barrier();  // ph3's trailing barrier merges with tile top
    }
  }

  // ---- epilogue: scatter into Q/K/V (256-wide n-tile never crosses 768-splits)
  const int which = n0 / 768;
  const int rem0 = n0 % 768;
  bf16_t* dst = which == 0 ? Qo : (which == 1 ? Ko : Vo);
  const float qscale = which == 0 ? (0.125f * LOG2E) : 1.0f;
#pragma unroll
  for (int n = 0; n < 4; n++) {
    const int cc = wn * 64 + n * 16 + l16;
    const int rem = rem0 + cc;
    const int h = rem >> 6, hd = rem & 63;
    const float bv = bias[n0 + cc];
#pragma unroll
    for (int m = 0; m < 8; m++)
#pragma unroll
      for (int r = 0; r < 4; r++) {
        const int gr = m0 + wm * 128 + m * 16 + quad * 4 + r;
        const int bb = gr >> 11, s = gr & 2047;
        const float val = (acc[m][n][r] + bv) * qscale;
        dst[((size_t)((bb * NH + h) * SEQ + s)) * 64 + hd] = (bf16_t)val;
      }
  }
}

// ---------------------------------------------------------------- V transpose
__global__ __launch_bounds__(256) void vtrans_kernel(const bf16_t* __restrict__ V,
                                                     bf16_t* __restrict__ Vt) {
  __shared__ bf16_t tile[64][66];
  int bh = blockIdx.y, s0 = blockIdx.x * 64;
  int tid = threadIdx.x;
  int r = tid >> 4, c4 = (tid & 15) * 4;
  const bf16_t* src = V + (size_t)bh * SEQ * 64;
#pragma unroll
  for (int rr = r; rr < 64; rr += 16)
    *(bf16x4*)&tile[rr][c4] = *(const bf16x4*)&src[(size_t)(s0 + rr) * 64 + c4];
  __syncthreads();
  bf16_t* dst = Vt + (size_t)bh * 64 * SEQ;
#pragma unroll
  for (int hd = r; hd < 64; hd += 16) {
    bf16x4 o;
    o[0] = tile[c4 + 0][hd]; o[1] = tile[c4 + 1][hd];
    o[2] = tile[c4 + 2][hd]; o[3] = tile[c4 + 3][hd];
    *(bf16x4*)&dst[(size_t)hd * SEQ + s0 + c4] = o;
  }
}

// ---------------------------------------------------------------- flash attention
// R9/R11 structure verbatim (56-58us best; 4 waves x 32q, grid (48,16),
// triple-buffer LDS K/V, vmcnt(4), 1 barrier/tile, (256,3), T13 defer-max,
// ones-MFMA l-sum). R10 (8-wave) and R12 (2-wave) both regressed -> 4-wave
// is the measured optimum for this structure.
__global__ __launch_bounds__(256, 3) void attn_kernel(
    const bf16_t* __restrict__ Q, const bf16_t* __restrict__ Kg,
    const bf16_t* __restrict__ Vt, bf16_t* __restrict__ Out) {
  __shared__ __align__(16) bf16_t Ks[3][64 * 64];
  __shared__ __align__(16) bf16_t Vs[3][64 * 64];
  const int tid = threadIdx.x;
  const int w = tid >> 6, lane = tid & 63;
  const int l31 = lane & 31, hi = lane >> 5;
  const int bh = blockIdx.x;
  const int b = bh / NH, h = bh % NH;
  const int qt = (int)(gridDim.y - 1) - (int)blockIdx.y;
  const int r0 = qt * 128 + w * 32;
  const int qrow = r0 + l31;
  const bf16_t* Qp = Q + (size_t)bh * SEQ * 64;
  const bf16_t* Kp = Kg + (size_t)bh * SEQ * 64;
  const bf16_t* Vp = Vt + (size_t)bh * 64 * SEQ;

  bf16x8 qf[4];
#pragma unroll
  for (int kc = 0; kc < 4; kc++)
    qf[kc] = *(const bf16x8*)&Qp[(size_t)qrow * 64 + kc * 16 + hi * 8];

  bf16x8 ones;
#pragma unroll
  for (int j = 0; j < 8; j++) ones[j] = (bf16_t)1.0f;

  float m_i = -1e30f;
  floatx16 accT[2];
  accT[0] = (floatx16)(0.f);
  accT[1] = (floatx16)(0.f);
  floatx16 zl = (floatx16)(0.f);

  const int nt_w = (r0 >> 6) + 1;
  const int ntmax = 2 * qt + 2;

  int srow[2], scolb[2];
#pragma unroll
  for (int r = 0; r < 2; r++) {
    int off = r * 4096 + w * 1024 + lane * 16;
    int row = off >> 7;
    srow[r] = row;
    scolb[r] = (off & 127) ^ ((row & 7) << 4);
  }

  auto stage = [&](int buf, int kt) {
    const int kbase = kt * 64;
#pragma unroll
    for (int r = 0; r < 2; r++) {
      gload_lds16(Kp + (size_t)(kbase + srow[r]) * 64 + (scolb[r] >> 1),
                  &Ks[buf][r * 2048 + w * 512]);
      gload_lds16(Vp + (size_t)srow[r] * SEQ + kbase + (scolb[r] >> 1),
                  &Vs[buf][r * 2048 + w * 512]);
    }
  };

  const int swz = (l31 & 7) << 4;

  stage(0, 0);

  int cur = 0;
  for (int kt = 0; kt < ntmax; kt++) {
    const int nxt = (cur == 2) ? 0 : cur + 1;
    if (kt + 1 < ntmax) {
      stage(nxt, kt + 1);
      asm volatile("s_waitcnt vmcnt(4)" ::: "memory");
    } else {
      asm volatile("s_waitcnt vmcnt(0)" ::: "memory");
    }
    __builtin_amdgcn_s_barrier();

    if (kt < nt_w) {
      const int kbase = kt * 64;
      const bf16_t* Kb = Ks[cur];
      const bf16_t* Vb = Vs[cur];
      floatx16 st[2];
#pragma unroll
      for (int kt2 = 0; kt2 < 2; kt2++) {
        const int row = kt2 * 32 + l31;
        floatx16 z = (floatx16)(0.f);
#pragma unroll
        for (int kc = 0; kc < 4; kc++) {
          bf16x8 kfr = *(const bf16x8*)&Kb[row * 64 + (((kc * 32 + hi * 16) ^ swz) >> 1)];
          z = __builtin_amdgcn_mfma_f32_32x32x16_bf16(kfr, qf[kc], z, 0, 0, 0);
        }
        st[kt2] = z;
      }
      if (kt == nt_w - 1) {
#pragma unroll
        for (int kt2 = 0; kt2 < 2; kt2++)
#pragma unroll
          for (int r = 0; r < 16; r++) {
            int key = kbase + kt2 * 32 + (r & 3) + 8 * (r >> 2) + 4 * hi;
            if (key > qrow) st[kt2][r] = -1e30f;
          }
      }
      float mloc = -1e30f;
#pragma unroll
      for (int kt2 = 0; kt2 < 2; kt2++)
#pragma unroll
        for (int r = 0; r < 16; r++) mloc = fmaxf(mloc, st[kt2][r]);
      mloc = fmaxf(mloc, __shfl_xor(mloc, 32));
      if (!__all((int)(mloc - m_i <= 8.f))) {
        const float mnew = fmaxf(m_i, mloc);
        const float al = __builtin_amdgcn_exp2f(m_i - mnew);
        m_i = mnew;
#pragma unroll
        for (int r = 0; r < 16; r++) zl[r] *= al;
#pragma unroll
        for (int dt = 0; dt < 2; dt++)
#pragma unroll
          for (int r = 0; r < 16; r++) accT[dt][r] *= al;
      }
#pragma unroll
      for (int kt2 = 0; kt2 < 2; kt2++)
#pragma unroll
        for (int r = 0; r < 16; r++)
          st[kt2][r] = __builtin_amdgcn_exp2f(st[kt2][r] - m_i);
#pragma unroll
      for (int kt2 = 0; kt2 < 2; kt2++) {
        unsigned int wds[8];
#pragma unroll
        for (int j = 0; j < 8; j++) wds[j] = pack2(st[kt2][2 * j], st[kt2][2 * j + 1]);
        unsigned int x0 = (unsigned int)__shfl_xor((int)(hi ? wds[0] : wds[2]), 32);
        unsigned int x1 = (unsigned int)__shfl_xor((int)(hi ? wds[1] : wds[3]), 32);
        unsigned int x2 = (unsigned int)__shfl_xor((int)(hi ? wds[4] : wds[6]), 32);
        unsigned int x3 = (unsigned int)__shfl_xor((int)(hi ? wds[5] : wds[7]), 32);
        u32x4 f0 = hi ? (u32x4){x0, x1, wds[2], wds[3]} : (u32x4){wds[0], wds[1], x0, x1};
        u32x4 f1 = hi ? (u32x4){x2, x3, wds[6], wds[7]} : (u32x4){wds[4], wds[5], x2, x3};
        bf16x8 pf0 = __builtin_bit_cast(bf16x8, f0);
        bf16x8 pf1 = __builtin_bit_cast(bf16x8, f1);
        zl = __builtin_amdgcn_mfma_f32_32x32x16_bf16(ones, pf0, zl, 0, 0, 0);
        zl = __builtin_amdgcn_mfma_f32_32x32x16_bf16(ones, pf1, zl, 0, 0, 0);
#pragma unroll
        for (int dt = 0; dt < 2; dt++) {
          const int vrow = dt * 32 + l31;
          bf16x8 v0 = *(const bf16x8*)&Vb[vrow * 64 + (((kt2 * 64 + hi * 16) ^ swz) >> 1)];
          bf16x8 v1 = *(const bf16x8*)&Vb[vrow * 64 + (((kt2 * 64 + 32 + hi * 16) ^ swz) >> 1)];
          accT[dt] = __builtin_amdgcn_mfma_f32_32x32x16_bf16(v0, pf0, accT[dt], 0, 0, 0);
          accT[dt] = __builtin_amdgcn_mfma_f32_32x32x16_bf16(v1, pf1, accT[dt], 0, 0, 0);
        }
      }
    }
    cur = nxt;
  }

  const float inv_l = 1.0f / zl[0];
#pragma unroll
  for (int dt = 0; dt < 2; dt++)
#pragma unroll
    for (int g = 0; g < 4; g++) {
      bf16x4 o;
#pragma unroll
      for (int j = 0; j < 4; j++) o[j] = (bf16_t)(accT[dt][4 * g + j] * inv_l);
      int d = dt * 32 + 8 * g + 4 * hi;
      *(bf16x4*)&Out[((size_t)(b * SEQ + qrow)) * DM + h * 64 + d] = o;
    }
}

// ---------------------------------------------------------------- out-proj GEMM (m97 single-buffer, BK=32)
__global__ __launch_bounds__(256) void gemm_proj_kernel(
    const bf16_t* __restrict__ A, const bf16_t* __restrict__ BT,
    const float* __restrict__ bias, float* __restrict__ out) {
  const int K = 768;
  __shared__ __align__(16) bf16_t As[128][32];
  __shared__ __align__(16) bf16_t Bs[128][32];
  const int m0 = blockIdx.x * 128, n0 = blockIdx.y * 128;
  const int tid = threadIdx.x;
  const int w = tid >> 6, lane = tid & 63, quad = lane >> 4, l16 = lane & 15;
  const int wm = w >> 1, wn = w & 1;
  const int ldrow = w * 32;
  const int grow = lane >> 2;
  const int gcol = (lane & 3) * 8;

  floatx4 acc[4][4];
#pragma unroll
  for (int mt = 0; mt < 4; mt++)
#pragma unroll
    for (int nt = 0; nt < 4; nt++) acc[mt][nt] = (floatx4)(0.f);

  const bf16_t* ga0 = A + (size_t)(m0 + ldrow) * K;
  const bf16_t* gb0 = BT + (size_t)(n0 + ldrow) * K;

  for (int k0 = 0; k0 < K; k0 += 32) {
    __syncthreads();
    gload_lds16(ga0 + (size_t)grow * K + k0 + gcol,        &As[ldrow][0]);
    gload_lds16(ga0 + (size_t)(grow + 16) * K + k0 + gcol, &As[ldrow + 16][0]);
    gload_lds16(gb0 + (size_t)grow * K + k0 + gcol,        &Bs[ldrow][0]);
    gload_lds16(gb0 + (size_t)(grow + 16) * K + k0 + gcol, &Bs[ldrow + 16][0]);
    __syncthreads();
    bf16x8 af[4], bfr[4];
#pragma unroll
    for (int mt = 0; mt < 4; mt++)
      af[mt] = *(const bf16x8*)&As[wm * 64 + mt * 16 + l16][quad * 8];
#pragma unroll
    for (int nt = 0; nt < 4; nt++)
      bfr[nt] = *(const bf16x8*)&Bs[wn * 64 + nt * 16 + l16][quad * 8];
#pragma unroll
    for (int mt = 0; mt < 4; mt++)
#pragma unroll
      for (int nt = 0; nt < 4; nt++)
        acc[mt][nt] = __builtin_amdgcn_mfma_f32_16x16x32_bf16(af[mt], bfr[nt], acc[mt][nt], 0, 0, 0);
  }

#pragma unroll
  for (int nt = 0; nt < 4; nt++) {
    const int gc = n0 + wn * 64 + nt * 16 + l16;
    const float bv = bias[gc];
#pragma unroll
    for (int mt = 0; mt < 4; mt++)
#pragma unroll
      for (int r = 0; r < 4; r++) {
        const int gr = m0 + wm * 64 + mt * 16 + quad * 4 + r;
        out[(size_t)gr * 768 + gc] = acc[mt][nt][r] + bv;
      }
  }
}

// ---------------------------------------------------------------- launch
extern "C" void kernel_launch(void* const* d_in, const int* in_sizes, int n_in,
                              void* d_out, int out_size, void* d_ws, size_t ws_size,
                              hipStream_t stream) {
  const float* x      = (const float*)d_in[0];
  const float* w_qkv  = (const float*)d_in[1];
  const float* b_qkv  = (const float*)d_in[2];
  const float* w_proj = (const float*)d_in[3];
  const float* b_proj = (const float*)d_in[4];
  float* out = (float*)d_out;
  char* ws = (char*)d_ws;

  // workspace layout (all 16B-aligned), total 67,633,152 B
  bf16_t* xb     = (bf16_t*)(ws + 0);         // 8192*768  bf16 (dead after gemm_qkv)
  bf16_t* wqkvT  = (bf16_t*)(ws + 12582912);  // 2304*768  bf16
  bf16_t* wprojT = (bf16_t*)(ws + 16121856);  //  768*768  bf16
  bf16_t* q      = (bf16_t*)(ws + 17301504);  // [4][12][2048][64] bf16
  bf16_t* k      = (bf16_t*)(ws + 29884416);
  bf16_t* v      = (bf16_t*)(ws + 42467328);
  bf16_t* ao     = (bf16_t*)(ws + 55050240);  // [8192][768] bf16
  bf16_t* vt     = xb;                        // aliases xb: [4][12][64][2048] bf16

  prep_kernel<<<8448, 256, 0, stream>>>(x, xb, w_qkv, wqkvT, w_proj, wprojT);
  gemm_qkv_kernel<<<dim3(32, 9), 512, 0, stream>>>(xb, wqkvT, b_qkv, q, k, v);
  vtrans_kernel<<<dim3(32, 48), 256, 0, stream>>>(v, vt);
  attn_kernel<<<dim3(48, 16), 256, 0, stream>>>(q, k, vt, ao);
  gemm_proj_kernel<<<dim3(64, 6), 256, 0, stream>>>(ao, wprojT, b_proj, out);
}

// Round 14
// 216.136 us; speedup vs baseline: 1.0144x; 1.0031x over previous
//
#include <hip/hip_runtime.h>
#include <hip/hip_bf16.h>
#include <cstdint>

typedef __bf16 bf16_t;
typedef __bf16 bf16x4 __attribute__((ext_vector_type(4)));
typedef __bf16 bf16x8 __attribute__((ext_vector_type(8)));
typedef float floatx4 __attribute__((ext_vector_type(4)));
typedef float floatx16 __attribute__((ext_vector_type(16)));
typedef unsigned int u32x4 __attribute__((ext_vector_type(4)));

#define NB 4
#define NH 12
#define SEQ 2048
#define DM 768
#define LOG2E 1.44269504088896340736f

// async global->LDS, 16B per lane; LDS dest is wave-uniform base + lane*16
__device__ __forceinline__ void gload_lds16(const bf16_t* g, bf16_t* l) {
  auto gp = reinterpret_cast<const __attribute__((address_space(1))) uint32_t*>(
      reinterpret_cast<uintptr_t>(g));
  auto lp = reinterpret_cast<__attribute__((address_space(3))) uint32_t*>(
      reinterpret_cast<uintptr_t>(l));
  __builtin_amdgcn_global_load_lds(gp, lp, 16, 0, 0);
}

// pack two f32 -> one dword of 2 bf16 (lo = a, hi = b)
__device__ __forceinline__ unsigned int pack2(float a, float b) {
  bf16_t x = (bf16_t)a, y = (bf16_t)b;
  unsigned short ux = __builtin_bit_cast(unsigned short, x);
  unsigned short uy = __builtin_bit_cast(unsigned short, y);
  return (unsigned int)ux | ((unsigned int)uy << 16);
}

// ---------------------------------------------------------------- fused prep
__global__ __launch_bounds__(256) void prep_kernel(
    const float* __restrict__ x, bf16_t* __restrict__ xb,
    const float* __restrict__ wqkv, bf16_t* __restrict__ wqkvT,
    const float* __restrict__ wproj, bf16_t* __restrict__ wprojT) {
  const int bid = blockIdx.x;
  const int tid = threadIdx.x;
  if (bid < 6144) {
    int i = (bid * 256 + tid) * 4;
    float4 v = *(const float4*)(x + i);
    bf16x4 hh;
    hh[0] = (bf16_t)v.x; hh[1] = (bf16_t)v.y; hh[2] = (bf16_t)v.z; hh[3] = (bf16_t)v.w;
    *(bf16x4*)(xb + i) = hh;
    return;
  }
  const float* in;
  bf16_t* out;
  int N, nb, kb;
  if (bid < 7872) {
    int t = bid - 6144;
    in = wqkv; out = wqkvT; N = 2304;
    nb = (t % 72) * 32; kb = (t / 72) * 32;
  } else {
    int t = bid - 7872;
    in = wproj; out = wprojT; N = 768;
    nb = (t % 24) * 32; kb = (t / 24) * 32;
  }
  const int K = 768;
  __shared__ float tile[32][33];
  int tx = tid & 31, ty = tid >> 5;
#pragma unroll
  for (int r = ty; r < 32; r += 8)
    tile[r][tx] = in[(size_t)(kb + r) * N + nb + tx];
  __syncthreads();
#pragma unroll
  for (int r = ty; r < 32; r += 8)
    out[(size_t)(nb + r) * K + kb + tx] = (bf16_t)tile[tx][r];
}

// ---------------------------------------------------------------- QKV GEMM (m97 128², BK=32 — proven; R13's 256² 8-phase regressed: 1 blk/CU + 288-block tail)
__global__ __launch_bounds__(256) void gemm_qkv_kernel(
    const bf16_t* __restrict__ A, const bf16_t* __restrict__ BT,
    const float* __restrict__ bias,
    bf16_t* __restrict__ Qo, bf16_t* __restrict__ Ko, bf16_t* __restrict__ Vo) {
  const int K = 768;
  __shared__ __align__(16) bf16_t As[128][32];
  __shared__ __align__(16) bf16_t Bs[128][32];
  const int m0 = blockIdx.x * 128, n0 = blockIdx.y * 128;
  const int tid = threadIdx.x;
  const int w = tid >> 6, lane = tid & 63, quad = lane >> 4, l16 = lane & 15;
  const int wm = w >> 1, wn = w & 1;
  const int ldrow = w * 32;
  const int grow = lane >> 2;
  const int gcol = (lane & 3) * 8;

  floatx4 acc[4][4];
#pragma unroll
  for (int mt = 0; mt < 4; mt++)
#pragma unroll
    for (int nt = 0; nt < 4; nt++) acc[mt][nt] = (floatx4)(0.f);

  const bf16_t* ga0 = A + (size_t)(m0 + ldrow) * K;
  const bf16_t* gb0 = BT + (size_t)(n0 + ldrow) * K;

  for (int k0 = 0; k0 < K; k0 += 32) {
    __syncthreads();
    gload_lds16(ga0 + (size_t)grow * K + k0 + gcol,        &As[ldrow][0]);
    gload_lds16(ga0 + (size_t)(grow + 16) * K + k0 + gcol, &As[ldrow + 16][0]);
    gload_lds16(gb0 + (size_t)grow * K + k0 + gcol,        &Bs[ldrow][0]);
    gload_lds16(gb0 + (size_t)(grow + 16) * K + k0 + gcol, &Bs[ldrow + 16][0]);
    __syncthreads();
    bf16x8 af[4], bfr[4];
#pragma unroll
    for (int mt = 0; mt < 4; mt++)
      af[mt] = *(const bf16x8*)&As[wm * 64 + mt * 16 + l16][quad * 8];
#pragma unroll
    for (int nt = 0; nt < 4; nt++)
      bfr[nt] = *(const bf16x8*)&Bs[wn * 64 + nt * 16 + l16][quad * 8];
#pragma unroll
    for (int mt = 0; mt < 4; mt++)
#pragma unroll
      for (int nt = 0; nt < 4; nt++)
        acc[mt][nt] = __builtin_amdgcn_mfma_f32_16x16x32_bf16(af[mt], bfr[nt], acc[mt][nt], 0, 0, 0);
  }

  const int which = n0 / 768;
  const int rem0 = n0 % 768;
  bf16_t* dst = which == 0 ? Qo : (which == 1 ? Ko : Vo);
  const float qscale = which == 0 ? (0.125f * LOG2E) : 1.0f;
#pragma unroll
  for (int nt = 0; nt < 4; nt++) {
    const int cc = wn * 64 + nt * 16 + l16;
    const int rem = rem0 + cc;
    const int h = rem >> 6, hd = rem & 63;
    const float bv = bias[n0 + cc];
#pragma unroll
    for (int mt = 0; mt < 4; mt++)
#pragma unroll
      for (int r = 0; r < 4; r++) {
        const int gr = m0 + wm * 64 + mt * 16 + quad * 4 + r;
        const int bb = gr >> 11, s = gr & 2047;
        const float val = (acc[mt][nt][r] + bv) * qscale;
        dst[((size_t)((bb * NH + h) * SEQ + s)) * 64 + hd] = (bf16_t)val;
      }
  }
}

// ---------------------------------------------------------------- V transpose
__global__ __launch_bounds__(256) void vtrans_kernel(const bf16_t* __restrict__ V,
                                                     bf16_t* __restrict__ Vt) {
  __shared__ bf16_t tile[64][66];
  int bh = blockIdx.y, s0 = blockIdx.x * 64;
  int tid = threadIdx.x;
  int r = tid >> 4, c4 = (tid & 15) * 4;
  const bf16_t* src = V + (size_t)bh * SEQ * 64;
#pragma unroll
  for (int rr = r; rr < 64; rr += 16)
    *(bf16x4*)&tile[rr][c4] = *(const bf16x4*)&src[(size_t)(s0 + rr) * 64 + c4];
  __syncthreads();
  bf16_t* dst = Vt + (size_t)bh * 64 * SEQ;
#pragma unroll
  for (int hd = r; hd < 64; hd += 16) {
    bf16x4 o;
    o[0] = tile[c4 + 0][hd]; o[1] = tile[c4 + 1][hd];
    o[2] = tile[c4 + 2][hd]; o[3] = tile[c4 + 3][hd];
    *(bf16x4*)&dst[(size_t)hd * SEQ + s0 + c4] = o;
  }
}

// ---------------------------------------------------------------- flash attention
// Proven inner structure (R9/R11: 4 waves, triple-buffer LDS K/V, vmcnt(4),
// 1 barrier/iter, T13 defer-max, ones-MFMA l-sum). NEW: PAIRED-STRIP balance —
// grid (48,8); block y processes q-strips (15-y) then (y) sequentially. Every
// block does exactly 34 tile-iters (2(15-y)+2 + 2y+2 = 36... constant), so
// every CU carries identical load (R9-R12 analysis: wall tracked the most-
// loaded CU, whose iter count ranged 32-64 under heaviest-first). Inter-strip
// s_barrier separates strip-1's last buffer reads from strip-2's prologue
// stage (barrier count stays wave-uniform).
__global__ __launch_bounds__(256, 3) void attn_kernel(
    const bf16_t* __restrict__ Q, const bf16_t* __restrict__ Kg,
    const bf16_t* __restrict__ Vt, bf16_t* __restrict__ Out) {
  __shared__ __align__(16) bf16_t Ks[3][64 * 64];
  __shared__ __align__(16) bf16_t Vs[3][64 * 64];
  const int tid = threadIdx.x;
  const int w = tid >> 6, lane = tid & 63;
  const int l31 = lane & 31, hi = lane >> 5;
  const int bh = blockIdx.x;
  const int b = bh / NH, h = bh % NH;
  const bf16_t* Qp = Q + (size_t)bh * SEQ * 64;
  const bf16_t* Kp = Kg + (size_t)bh * SEQ * 64;
  const bf16_t* Vp = Vt + (size_t)bh * 64 * SEQ;

  bf16x8 ones;
#pragma unroll
  for (int j = 0; j < 8; j++) ones[j] = (bf16_t)1.0f;

  // staging geometry: round r covers LDS bytes [r*4096 + w*1024 + lane*16, +16)
  int srow[2], scolb[2];
#pragma unroll
  for (int r = 0; r < 2; r++) {
    int off = r * 4096 + w * 1024 + lane * 16;
    int row = off >> 7;
    srow[r] = row;
    scolb[r] = (off & 127) ^ ((row & 7) << 4);
  }

  auto stage = [&](int buf, int kt) {
    const int kbase = kt * 64;
#pragma unroll
    for (int r = 0; r < 2; r++) {
      gload_lds16(Kp + (size_t)(kbase + srow[r]) * 64 + (scolb[r] >> 1),
                  &Ks[buf][r * 2048 + w * 512]);
      gload_lds16(Vp + (size_t)srow[r] * SEQ + kbase + (scolb[r] >> 1),
                  &Vs[buf][r * 2048 + w * 512]);
    }
  };

  const int swz = (l31 & 7) << 4;

  for (int half = 0; half < 2; half++) {
    const int qt = half == 0 ? (15 - (int)blockIdx.y) : (int)blockIdx.y;
    const int r0 = qt * 128 + w * 32;
    const int qrow = r0 + l31;

    bf16x8 qf[4];
#pragma unroll
    for (int kc = 0; kc < 4; kc++)
      qf[kc] = *(const bf16x8*)&Qp[(size_t)qrow * 64 + kc * 16 + hi * 8];

    float m_i = -1e30f;
    floatx16 accT[2];
    accT[0] = (floatx16)(0.f);
    accT[1] = (floatx16)(0.f);
    floatx16 zl = (floatx16)(0.f);

    const int nt_w = (r0 >> 6) + 1;
    const int ntmax = 2 * qt + 2;

    stage(0, 0);

    int cur = 0;
    for (int kt = 0; kt < ntmax; kt++) {
      const int nxt = (cur == 2) ? 0 : cur + 1;
      if (kt + 1 < ntmax) {
        stage(nxt, kt + 1);
        asm volatile("s_waitcnt vmcnt(4)" ::: "memory");
      } else {
        asm volatile("s_waitcnt vmcnt(0)" ::: "memory");
      }
      __builtin_amdgcn_s_barrier();

      if (kt < nt_w) {
        const int kbase = kt * 64;
        const bf16_t* Kb = Ks[cur];
        const bf16_t* Vb = Vs[cur];
        floatx16 st[2];
#pragma unroll
        for (int kt2 = 0; kt2 < 2; kt2++) {
          const int row = kt2 * 32 + l31;
          floatx16 z = (floatx16)(0.f);
#pragma unroll
          for (int kc = 0; kc < 4; kc++) {
            bf16x8 kfr = *(const bf16x8*)&Kb[row * 64 + (((kc * 32 + hi * 16) ^ swz) >> 1)];
            z = __builtin_amdgcn_mfma_f32_32x32x16_bf16(kfr, qf[kc], z, 0, 0, 0);
          }
          st[kt2] = z;
        }
        if (kt == nt_w - 1) {
#pragma unroll
          for (int kt2 = 0; kt2 < 2; kt2++)
#pragma unroll
            for (int r = 0; r < 16; r++) {
              int key = kbase + kt2 * 32 + (r & 3) + 8 * (r >> 2) + 4 * hi;
              if (key > qrow) st[kt2][r] = -1e30f;
            }
        }
        float mloc = -1e30f;
#pragma unroll
        for (int kt2 = 0; kt2 < 2; kt2++)
#pragma unroll
          for (int r = 0; r < 16; r++) mloc = fmaxf(mloc, st[kt2][r]);
        mloc = fmaxf(mloc, __shfl_xor(mloc, 32));
        if (!__all((int)(mloc - m_i <= 8.f))) {
          const float mnew = fmaxf(m_i, mloc);
          const float al = __builtin_amdgcn_exp2f(m_i - mnew);
          m_i = mnew;
#pragma unroll
          for (int r = 0; r < 16; r++) zl[r] *= al;
#pragma unroll
          for (int dt = 0; dt < 2; dt++)
#pragma unroll
            for (int r = 0; r < 16; r++) accT[dt][r] *= al;
        }
#pragma unroll
        for (int kt2 = 0; kt2 < 2; kt2++)
#pragma unroll
          for (int r = 0; r < 16; r++)
            st[kt2][r] = __builtin_amdgcn_exp2f(st[kt2][r] - m_i);
#pragma unroll
        for (int kt2 = 0; kt2 < 2; kt2++) {
          unsigned int wds[8];
#pragma unroll
          for (int j = 0; j < 8; j++) wds[j] = pack2(st[kt2][2 * j], st[kt2][2 * j + 1]);
          unsigned int x0 = (unsigned int)__shfl_xor((int)(hi ? wds[0] : wds[2]), 32);
          unsigned int x1 = (unsigned int)__shfl_xor((int)(hi ? wds[1] : wds[3]), 32);
          unsigned int x2 = (unsigned int)__shfl_xor((int)(hi ? wds[4] : wds[6]), 32);
          unsigned int x3 = (unsigned int)__shfl_xor((int)(hi ? wds[5] : wds[7]), 32);
          u32x4 f0 = hi ? (u32x4){x0, x1, wds[2], wds[3]} : (u32x4){wds[0], wds[1], x0, x1};
          u32x4 f1 = hi ? (u32x4){x2, x3, wds[6], wds[7]} : (u32x4){wds[4], wds[5], x2, x3};
          bf16x8 pf0 = __builtin_bit_cast(bf16x8, f0);
          bf16x8 pf1 = __builtin_bit_cast(bf16x8, f1);
          zl = __builtin_amdgcn_mfma_f32_32x32x16_bf16(ones, pf0, zl, 0, 0, 0);
          zl = __builtin_amdgcn_mfma_f32_32x32x16_bf16(ones, pf1, zl, 0, 0, 0);
#pragma unroll
          for (int dt = 0; dt < 2; dt++) {
            const int vrow = dt * 32 + l31;
            bf16x8 v0 = *(const bf16x8*)&Vb[vrow * 64 + (((kt2 * 64 + hi * 16) ^ swz) >> 1)];
            bf16x8 v1 = *(const bf16x8*)&Vb[vrow * 64 + (((kt2 * 64 + 32 + hi * 16) ^ swz) >> 1)];
            accT[dt] = __builtin_amdgcn_mfma_f32_32x32x16_bf16(v0, pf0, accT[dt], 0, 0, 0);
            accT[dt] = __builtin_amdgcn_mfma_f32_32x32x16_bf16(v1, pf1, accT[dt], 0, 0, 0);
          }
        }
      }
      cur = nxt;
    }

    // epilogue for this strip
    const float inv_l = 1.0f / zl[0];
#pragma unroll
    for (int dt = 0; dt < 2; dt++)
#pragma unroll
      for (int g = 0; g < 4; g++) {
        bf16x4 o;
#pragma unroll
        for (int j = 0; j < 4; j++) o[j] = (bf16_t)(accT[dt][4 * g + j] * inv_l);
        int d = dt * 32 + 8 * g + 4 * hi;
        *(bf16x4*)&Out[((size_t)(b * SEQ + qrow)) * DM + h * 64 + d] = o;
      }

    // separate strip-1's buffer reads from strip-2's prologue stage
    if (half == 0) __builtin_amdgcn_s_barrier();
  }
}

// ---------------------------------------------------------------- out-proj GEMM (m97 single-buffer, BK=32)
__global__ __launch_bounds__(256) void gemm_proj_kernel(
    const bf16_t* __restrict__ A, const bf16_t* __restrict__ BT,
    const float* __restrict__ bias, float* __restrict__ out) {
  const int K = 768;
  __shared__ __align__(16) bf16_t As[128][32];
  __shared__ __align__(16) bf16_t Bs[128][32];
  const int m0 = blockIdx.x * 128, n0 = blockIdx.y * 128;
  const int tid = threadIdx.x;
  const int w = tid >> 6, lane = tid & 63, quad = lane >> 4, l16 = lane & 15;
  const int wm = w >> 1, wn = w & 1;
  const int ldrow = w * 32;
  const int grow = lane >> 2;
  const int gcol = (lane & 3) * 8;

  floatx4 acc[4][4];
#pragma unroll
  for (int mt = 0; mt < 4; mt++)
#pragma unroll
    for (int nt = 0; nt < 4; nt++) acc[mt][nt] = (floatx4)(0.f);

  const bf16_t* ga0 = A + (size_t)(m0 + ldrow) * K;
  const bf16_t* gb0 = BT + (size_t)(n0 + ldrow) * K;

  for (int k0 = 0; k0 < K; k0 += 32) {
    __syncthreads();
    gload_lds16(ga0 + (size_t)grow * K + k0 + gcol,        &As[ldrow][0]);
    gload_lds16(ga0 + (size_t)(grow + 16) * K + k0 + gcol, &As[ldrow + 16][0]);
    gload_lds16(gb0 + (size_t)grow * K + k0 + gcol,        &Bs[ldrow][0]);
    gload_lds16(gb0 + (size_t)(grow + 16) * K + k0 + gcol, &Bs[ldrow + 16][0]);
    __syncthreads();
    bf16x8 af[4], bfr[4];
#pragma unroll
    for (int mt = 0; mt < 4; mt++)
      af[mt] = *(const bf16x8*)&As[wm * 64 + mt * 16 + l16][quad * 8];
#pragma unroll
    for (int nt = 0; nt < 4; nt++)
      bfr[nt] = *(const bf16x8*)&Bs[wn * 64 + nt * 16 + l16][quad * 8];
#pragma unroll
    for (int mt = 0; mt < 4; mt++)
#pragma unroll
      for (int nt = 0; nt < 4; nt++)
        acc[mt][nt] = __builtin_amdgcn_mfma_f32_16x16x32_bf16(af[mt], bfr[nt], acc[mt][nt], 0, 0, 0);
  }

#pragma unroll
  for (int nt = 0; nt < 4; nt++) {
    const int gc = n0 + wn * 64 + nt * 16 + l16;
    const float bv = bias[gc];
#pragma unroll
    for (int mt = 0; mt < 4; mt++)
#pragma unroll
      for (int r = 0; r < 4; r++) {
        const int gr = m0 + wm * 64 + mt * 16 + quad * 4 + r;
        out[(size_t)gr * 768 + gc] = acc[mt][nt][r] + bv;
      }
  }
}

// ---------------------------------------------------------------- launch
extern "C" void kernel_launch(void* const* d_in, const int* in_sizes, int n_in,
                              void* d_out, int out_size, void* d_ws, size_t ws_size,
                              hipStream_t stream) {
  const float* x      = (const float*)d_in[0];
  const float* w_qkv  = (const float*)d_in[1];
  const float* b_qkv  = (const float*)d_in[2];
  const float* w_proj = (const float*)d_in[3];
  const float* b_proj = (const float*)d_in[4];
  float* out = (float*)d_out;
  char* ws = (char*)d_ws;

  // workspace layout (all 16B-aligned), total 67,633,152 B
  bf16_t* xb     = (bf16_t*)(ws + 0);         // 8192*768  bf16 (dead after gemm_qkv)
  bf16_t* wqkvT  = (bf16_t*)(ws + 12582912);  // 2304*768  bf16
  bf16_t* wprojT = (bf16_t*)(ws + 16121856);  //  768*768  bf16
  bf16_t* q      = (bf16_t*)(ws + 17301504);  // [4][12][2048][64] bf16
  bf16_t* k      = (bf16_t*)(ws + 29884416);
  bf16_t* v      = (bf16_t*)(ws + 42467328);
  bf16_t* ao     = (bf16_t*)(ws + 55050240);  // [8192][768] bf16
  bf16_t* vt     = xb;                        // aliases xb: [4][12][64][2048] bf16

  prep_kernel<<<8448, 256, 0, stream>>>(x, xb, w_qkv, wqkvT, w_proj, wprojT);
  gemm_qkv_kernel<<<dim3(64, 18), 256, 0, stream>>>(xb, wqkvT, b_qkv, q, k, v);
  vtrans_kernel<<<dim3(32, 48), 256, 0, stream>>>(v, vt);
  attn_kernel<<<dim3(48, 8), 256, 0, stream>>>(q, k, vt, ao);
  gemm_proj_kernel<<<dim3(64, 6), 256, 0, stream>>>(ao, wprojT, b_proj, out);
}

// Round 15
// 212.647 us; speedup vs baseline: 1.0310x; 1.0164x over previous
//
#include <hip/hip_runtime.h>
#include <hip/hip_bf16.h>
#include <cstdint>

typedef __bf16 bf16_t;
typedef __bf16 bf16x4 __attribute__((ext_vector_type(4)));
typedef __bf16 bf16x8 __attribute__((ext_vector_type(8)));
typedef float floatx4 __attribute__((ext_vector_type(4)));
typedef float floatx16 __attribute__((ext_vector_type(16)));
typedef unsigned int u32x4 __attribute__((ext_vector_type(4)));

#define NB 4
#define NH 12
#define SEQ 2048
#define DM 768
#define LOG2E 1.44269504088896340736f

// async global->LDS, 16B per lane; LDS dest is wave-uniform base + lane*16
__device__ __forceinline__ void gload_lds16(const bf16_t* g, bf16_t* l) {
  auto gp = reinterpret_cast<const __attribute__((address_space(1))) uint32_t*>(
      reinterpret_cast<uintptr_t>(g));
  auto lp = reinterpret_cast<__attribute__((address_space(3))) uint32_t*>(
      reinterpret_cast<uintptr_t>(l));
  __builtin_amdgcn_global_load_lds(gp, lp, 16, 0, 0);
}

// pack two f32 -> one dword of 2 bf16 (lo = a, hi = b)
__device__ __forceinline__ unsigned int pack2(float a, float b) {
  bf16_t x = (bf16_t)a, y = (bf16_t)b;
  unsigned short ux = __builtin_bit_cast(unsigned short, x);
  unsigned short uy = __builtin_bit_cast(unsigned short, y);
  return (unsigned int)ux | ((unsigned int)uy << 16);
}

// ---------------------------------------------------------------- fused prep
__global__ __launch_bounds__(256) void prep_kernel(
    const float* __restrict__ x, bf16_t* __restrict__ xb,
    const float* __restrict__ wqkv, bf16_t* __restrict__ wqkvT,
    const float* __restrict__ wproj, bf16_t* __restrict__ wprojT) {
  const int bid = blockIdx.x;
  const int tid = threadIdx.x;
  if (bid < 6144) {
    int i = (bid * 256 + tid) * 4;
    float4 v = *(const float4*)(x + i);
    bf16x4 hh;
    hh[0] = (bf16_t)v.x; hh[1] = (bf16_t)v.y; hh[2] = (bf16_t)v.z; hh[3] = (bf16_t)v.w;
    *(bf16x4*)(xb + i) = hh;
    return;
  }
  const float* in;
  bf16_t* out;
  int N, nb, kb;
  if (bid < 7872) {
    int t = bid - 6144;
    in = wqkv; out = wqkvT; N = 2304;
    nb = (t % 72) * 32; kb = (t / 72) * 32;
  } else {
    int t = bid - 7872;
    in = wproj; out = wprojT; N = 768;
    nb = (t % 24) * 32; kb = (t / 24) * 32;
  }
  const int K = 768;
  __shared__ float tile[32][33];
  int tx = tid & 31, ty = tid >> 5;
#pragma unroll
  for (int r = ty; r < 32; r += 8)
    tile[r][tx] = in[(size_t)(kb + r) * N + nb + tx];
  __syncthreads();
#pragma unroll
  for (int r = ty; r < 32; r += 8)
    out[(size_t)(nb + r) * K + kb + tx] = (bf16_t)tile[tx][r];
}

// ---------------------------------------------------------------- QKV GEMM (256x128 block, m97 inner loop)
// BM=256 x BN=128, BK=32, 512 thr = 8 waves (4m x 2n), each wave the PROVEN
// m97 64x64 sub-tile. Per K-step: 24KB staged / 128 MFMAs = 187 B/MFMA (vs
// 256 at 128^2) — A-tile reused across 2 n-wave columns; 3 staging loads/thr
// (was 4). Waves/CU unchanged (576 blks x 8 = 1152 x 4). No swizzle needed:
// 64B rows -> 2-way bank alias = free (m136).
__global__ __launch_bounds__(512) void gemm_qkv_kernel(
    const bf16_t* __restrict__ A, const bf16_t* __restrict__ BT,
    const float* __restrict__ bias,
    bf16_t* __restrict__ Qo, bf16_t* __restrict__ Ko, bf16_t* __restrict__ Vo) {
  const int K = 768;
  __shared__ __align__(16) bf16_t As[256 * 32];  // 16KB
  __shared__ __align__(16) bf16_t Bs[128 * 32];  // 8KB
  const int m0 = blockIdx.x * 256, n0 = blockIdx.y * 128;
  const int tid = threadIdx.x;
  const int w = tid >> 6, lane = tid & 63, quad = lane >> 4, l16 = lane & 15;
  const int wm = w >> 1, wn = w & 1;            // wm 0..3, wn 0..1
  const int sra = tid >> 2;                     // staging row 0..127
  const int scol = (tid & 3) * 8;               // staging col (bf16)

  floatx4 acc[4][4];
#pragma unroll
  for (int mt = 0; mt < 4; mt++)
#pragma unroll
    for (int nt = 0; nt < 4; nt++) acc[mt][nt] = (floatx4)(0.f);

  for (int k0 = 0; k0 < K; k0 += 32) {
    __syncthreads();
    gload_lds16(A + (size_t)(m0 + sra) * K + k0 + scol,       &As[w * 512]);
    gload_lds16(A + (size_t)(m0 + 128 + sra) * K + k0 + scol, &As[4096 + w * 512]);
    gload_lds16(BT + (size_t)(n0 + sra) * K + k0 + scol,      &Bs[w * 512]);
    __syncthreads();
    bf16x8 af[4], bfr[4];
#pragma unroll
    for (int mt = 0; mt < 4; mt++)
      af[mt] = *(const bf16x8*)&As[(wm * 64 + mt * 16 + l16) * 32 + quad * 8];
#pragma unroll
    for (int nt = 0; nt < 4; nt++)
      bfr[nt] = *(const bf16x8*)&Bs[(wn * 64 + nt * 16 + l16) * 32 + quad * 8];
#pragma unroll
    for (int mt = 0; mt < 4; mt++)
#pragma unroll
      for (int nt = 0; nt < 4; nt++)
        acc[mt][nt] = __builtin_amdgcn_mfma_f32_16x16x32_bf16(af[mt], bfr[nt], acc[mt][nt], 0, 0, 0);
  }

  const int which = n0 / 768;
  const int rem0 = n0 % 768;
  bf16_t* dst = which == 0 ? Qo : (which == 1 ? Ko : Vo);
  const float qscale = which == 0 ? (0.125f * LOG2E) : 1.0f;
#pragma unroll
  for (int nt = 0; nt < 4; nt++) {
    const int cc = wn * 64 + nt * 16 + l16;
    const int rem = rem0 + cc;
    const int h = rem >> 6, hd = rem & 63;
    const float bv = bias[n0 + cc];
#pragma unroll
    for (int mt = 0; mt < 4; mt++)
#pragma unroll
      for (int r = 0; r < 4; r++) {
        const int gr = m0 + wm * 64 + mt * 16 + quad * 4 + r;
        const int bb = gr >> 11, s = gr & 2047;
        const float val = (acc[mt][nt][r] + bv) * qscale;
        dst[((size_t)((bb * NH + h) * SEQ + s)) * 64 + hd] = (bf16_t)val;
      }
  }
}

// ---------------------------------------------------------------- V transpose
__global__ __launch_bounds__(256) void vtrans_kernel(const bf16_t* __restrict__ V,
                                                     bf16_t* __restrict__ Vt) {
  __shared__ bf16_t tile[64][66];
  int bh = blockIdx.y, s0 = blockIdx.x * 64;
  int tid = threadIdx.x;
  int r = tid >> 4, c4 = (tid & 15) * 4;
  const bf16_t* src = V + (size_t)bh * SEQ * 64;
#pragma unroll
  for (int rr = r; rr < 64; rr += 16)
    *(bf16x4*)&tile[rr][c4] = *(const bf16x4*)&src[(size_t)(s0 + rr) * 64 + c4];
  __syncthreads();
  bf16_t* dst = Vt + (size_t)bh * 64 * SEQ;
#pragma unroll
  for (int hd = r; hd < 64; hd += 16) {
    bf16x4 o;
    o[0] = tile[c4 + 0][hd]; o[1] = tile[c4 + 1][hd];
    o[2] = tile[c4 + 2][hd]; o[3] = tile[c4 + 3][hd];
    *(bf16x4*)&dst[(size_t)hd * SEQ + s0 + c4] = o;
  }
}

// ---------------------------------------------------------------- flash attention
// R9/R11 EXACT (56.2-58.7us measured best): 4 waves, grid (48,16), heaviest-
// first, triple-buffer LDS K/V, vmcnt(4), 1 barrier/iter, (256,3), T13
// defer-max, ones-MFMA l-sum. R10/R12/R14 all showed: any grid < ~768 blocks
// loses (block-level concurrency is the binding constraint, not balance).
__global__ __launch_bounds__(256, 3) void attn_kernel(
    const bf16_t* __restrict__ Q, const bf16_t* __restrict__ Kg,
    const bf16_t* __restrict__ Vt, bf16_t* __restrict__ Out) {
  __shared__ __align__(16) bf16_t Ks[3][64 * 64];
  __shared__ __align__(16) bf16_t Vs[3][64 * 64];
  const int tid = threadIdx.x;
  const int w = tid >> 6, lane = tid & 63;
  const int l31 = lane & 31, hi = lane >> 5;
  const int bh = blockIdx.x;
  const int b = bh / NH, h = bh % NH;
  const int qt = (int)(gridDim.y - 1) - (int)blockIdx.y;
  const int r0 = qt * 128 + w * 32;
  const int qrow = r0 + l31;
  const bf16_t* Qp = Q + (size_t)bh * SEQ * 64;
  const bf16_t* Kp = Kg + (size_t)bh * SEQ * 64;
  const bf16_t* Vp = Vt + (size_t)bh * 64 * SEQ;

  bf16x8 qf[4];
#pragma unroll
  for (int kc = 0; kc < 4; kc++)
    qf[kc] = *(const bf16x8*)&Qp[(size_t)qrow * 64 + kc * 16 + hi * 8];

  bf16x8 ones;
#pragma unroll
  for (int j = 0; j < 8; j++) ones[j] = (bf16_t)1.0f;

  float m_i = -1e30f;
  floatx16 accT[2];
  accT[0] = (floatx16)(0.f);
  accT[1] = (floatx16)(0.f);
  floatx16 zl = (floatx16)(0.f);

  const int nt_w = (r0 >> 6) + 1;
  const int ntmax = 2 * qt + 2;

  int srow[2], scolb[2];
#pragma unroll
  for (int r = 0; r < 2; r++) {
    int off = r * 4096 + w * 1024 + lane * 16;
    int row = off >> 7;
    srow[r] = row;
    scolb[r] = (off & 127) ^ ((row & 7) << 4);
  }

  auto stage = [&](int buf, int kt) {
    const int kbase = kt * 64;
#pragma unroll
    for (int r = 0; r < 2; r++) {
      gload_lds16(Kp + (size_t)(kbase + srow[r]) * 64 + (scolb[r] >> 1),
                  &Ks[buf][r * 2048 + w * 512]);
      gload_lds16(Vp + (size_t)srow[r] * SEQ + kbase + (scolb[r] >> 1),
                  &Vs[buf][r * 2048 + w * 512]);
    }
  };

  const int swz = (l31 & 7) << 4;

  stage(0, 0);

  int cur = 0;
  for (int kt = 0; kt < ntmax; kt++) {
    const int nxt = (cur == 2) ? 0 : cur + 1;
    if (kt + 1 < ntmax) {
      stage(nxt, kt + 1);
      asm volatile("s_waitcnt vmcnt(4)" ::: "memory");
    } else {
      asm volatile("s_waitcnt vmcnt(0)" ::: "memory");
    }
    __builtin_amdgcn_s_barrier();

    if (kt < nt_w) {
      const int kbase = kt * 64;
      const bf16_t* Kb = Ks[cur];
      const bf16_t* Vb = Vs[cur];
      floatx16 st[2];
#pragma unroll
      for (int kt2 = 0; kt2 < 2; kt2++) {
        const int row = kt2 * 32 + l31;
        floatx16 z = (floatx16)(0.f);
#pragma unroll
        for (int kc = 0; kc < 4; kc++) {
          bf16x8 kfr = *(const bf16x8*)&Kb[row * 64 + (((kc * 32 + hi * 16) ^ swz) >> 1)];
          z = __builtin_amdgcn_mfma_f32_32x32x16_bf16(kfr, qf[kc], z, 0, 0, 0);
        }
        st[kt2] = z;
      }
      if (kt == nt_w - 1) {
#pragma unroll
        for (int kt2 = 0; kt2 < 2; kt2++)
#pragma unroll
          for (int r = 0; r < 16; r++) {
            int key = kbase + kt2 * 32 + (r & 3) + 8 * (r >> 2) + 4 * hi;
            if (key > qrow) st[kt2][r] = -1e30f;
          }
      }
      float mloc = -1e30f;
#pragma unroll
      for (int kt2 = 0; kt2 < 2; kt2++)
#pragma unroll
        for (int r = 0; r < 16; r++) mloc = fmaxf(mloc, st[kt2][r]);
      mloc = fmaxf(mloc, __shfl_xor(mloc, 32));
      if (!__all((int)(mloc - m_i <= 8.f))) {
        const float mnew = fmaxf(m_i, mloc);
        const float al = __builtin_amdgcn_exp2f(m_i - mnew);
        m_i = mnew;
#pragma unroll
        for (int r = 0; r < 16; r++) zl[r] *= al;
#pragma unroll
        for (int dt = 0; dt < 2; dt++)
#pragma unroll
          for (int r = 0; r < 16; r++) accT[dt][r] *= al;
      }
#pragma unroll
      for (int kt2 = 0; kt2 < 2; kt2++)
#pragma unroll
        for (int r = 0; r < 16; r++)
          st[kt2][r] = __builtin_amdgcn_exp2f(st[kt2][r] - m_i);
#pragma unroll
      for (int kt2 = 0; kt2 < 2; kt2++) {
        unsigned int wds[8];
#pragma unroll
        for (int j = 0; j < 8; j++) wds[j] = pack2(st[kt2][2 * j], st[kt2][2 * j + 1]);
        unsigned int x0 = (unsigned int)__shfl_xor((int)(hi ? wds[0] : wds[2]), 32);
        unsigned int x1 = (unsigned int)__shfl_xor((int)(hi ? wds[1] : wds[3]), 32);
        unsigned int x2 = (unsigned int)__shfl_xor((int)(hi ? wds[4] : wds[6]), 32);
        unsigned int x3 = (unsigned int)__shfl_xor((int)(hi ? wds[5] : wds[7]), 32);
        u32x4 f0 = hi ? (u32x4){x0, x1, wds[2], wds[3]} : (u32x4){wds[0], wds[1], x0, x1};
        u32x4 f1 = hi ? (u32x4){x2, x3, wds[6], wds[7]} : (u32x4){wds[4], wds[5], x2, x3};
        bf16x8 pf0 = __builtin_bit_cast(bf16x8, f0);
        bf16x8 pf1 = __builtin_bit_cast(bf16x8, f1);
        zl = __builtin_amdgcn_mfma_f32_32x32x16_bf16(ones, pf0, zl, 0, 0, 0);
        zl = __builtin_amdgcn_mfma_f32_32x32x16_bf16(ones, pf1, zl, 0, 0, 0);
#pragma unroll
        for (int dt = 0; dt < 2; dt++) {
          const int vrow = dt * 32 + l31;
          bf16x8 v0 = *(const bf16x8*)&Vb[vrow * 64 + (((kt2 * 64 + hi * 16) ^ swz) >> 1)];
          bf16x8 v1 = *(const bf16x8*)&Vb[vrow * 64 + (((kt2 * 64 + 32 + hi * 16) ^ swz) >> 1)];
          accT[dt] = __builtin_amdgcn_mfma_f32_32x32x16_bf16(v0, pf0, accT[dt], 0, 0, 0);
          accT[dt] = __builtin_amdgcn_mfma_f32_32x32x16_bf16(v1, pf1, accT[dt], 0, 0, 0);
        }
      }
    }
    cur = nxt;
  }

  const float inv_l = 1.0f / zl[0];
#pragma unroll
  for (int dt = 0; dt < 2; dt++)
#pragma unroll
    for (int g = 0; g < 4; g++) {
      bf16x4 o;
#pragma unroll
      for (int j = 0; j < 4; j++) o[j] = (bf16_t)(accT[dt][4 * g + j] * inv_l);
      int d = dt * 32 + 8 * g + 4 * hi;
      *(bf16x4*)&Out[((size_t)(b * SEQ + qrow)) * DM + h * 64 + d] = o;
    }
}

// ---------------------------------------------------------------- out-proj GEMM (m97 single-buffer, BK=32)
__global__ __launch_bounds__(256) void gemm_proj_kernel(
    const bf16_t* __restrict__ A, const bf16_t* __restrict__ BT,
    const float* __restrict__ bias, float* __restrict__ out) {
  const int K = 768;
  __shared__ __align__(16) bf16_t As[128][32];
  __shared__ __align__(16) bf16_t Bs[128][32];
  const int m0 = blockIdx.x * 128, n0 = blockIdx.y * 128;
  const int tid = threadIdx.x;
  const int w = tid >> 6, lane = tid & 63, quad = lane >> 4, l16 = lane & 15;
  const int wm = w >> 1, wn = w & 1;
  const int ldrow = w * 32;
  const int grow = lane >> 2;
  const int gcol = (lane & 3) * 8;

  floatx4 acc[4][4];
#pragma unroll
  for (int mt = 0; mt < 4; mt++)
#pragma unroll
    for (int nt = 0; nt < 4; nt++) acc[mt][nt] = (floatx4)(0.f);

  const bf16_t* ga0 = A + (size_t)(m0 + ldrow) * K;
  const bf16_t* gb0 = BT + (size_t)(n0 + ldrow) * K;

  for (int k0 = 0; k0 < K; k0 += 32) {
    __syncthreads();
    gload_lds16(ga0 + (size_t)grow * K + k0 + gcol,        &As[ldrow][0]);
    gload_lds16(ga0 + (size_t)(grow + 16) * K + k0 + gcol, &As[ldrow + 16][0]);
    gload_lds16(gb0 + (size_t)grow * K + k0 + gcol,        &Bs[ldrow][0]);
    gload_lds16(gb0 + (size_t)(grow + 16) * K + k0 + gcol, &Bs[ldrow + 16][0]);
    __syncthreads();
    bf16x8 af[4], bfr[4];
#pragma unroll
    for (int mt = 0; mt < 4; mt++)
      af[mt] = *(const bf16x8*)&As[wm * 64 + mt * 16 + l16][quad * 8];
#pragma unroll
    for (int nt = 0; nt < 4; nt++)
      bfr[nt] = *(const bf16x8*)&Bs[wn * 64 + nt * 16 + l16][quad * 8];
#pragma unroll
    for (int mt = 0; mt < 4; mt++)
#pragma unroll
      for (int nt = 0; nt < 4; nt++)
        acc[mt][nt] = __builtin_amdgcn_mfma_f32_16x16x32_bf16(af[mt], bfr[nt], acc[mt][nt], 0, 0, 0);
  }

#pragma unroll
  for (int nt = 0; nt < 4; nt++) {
    const int gc = n0 + wn * 64 + nt * 16 + l16;
    const float bv = bias[gc];
#pragma unroll
    for (int mt = 0; mt < 4; mt++)
#pragma unroll
      for (int r = 0; r < 4; r++) {
        const int gr = m0 + wm * 64 + mt * 16 + quad * 4 + r;
        out[(size_t)gr * 768 + gc] = acc[mt][nt][r] + bv;
      }
  }
}

// ---------------------------------------------------------------- launch
extern "C" void kernel_launch(void* const* d_in, const int* in_sizes, int n_in,
                              void* d_out, int out_size, void* d_ws, size_t ws_size,
                              hipStream_t stream) {
  const float* x      = (const float*)d_in[0];
  const float* w_qkv  = (const float*)d_in[1];
  const float* b_qkv  = (const float*)d_in[2];
  const float* w_proj = (const float*)d_in[3];
  const float* b_proj = (const float*)d_in[4];
  float* out = (float*)d_out;
  char* ws = (char*)d_ws;

  // workspace layout (all 16B-aligned), total 67,633,152 B
  bf16_t* xb     = (bf16_t*)(ws + 0);         // 8192*768  bf16 (dead after gemm_qkv)
  bf16_t* wqkvT  = (bf16_t*)(ws + 12582912);  // 2304*768  bf16
  bf16_t* wprojT = (bf16_t*)(ws + 16121856);  //  768*768  bf16
  bf16_t* q      = (bf16_t*)(ws + 17301504);  // [4][12][2048][64] bf16
  bf16_t* k      = (bf16_t*)(ws + 29884416);
  bf16_t* v      = (bf16_t*)(ws + 42467328);
  bf16_t* ao     = (bf16_t*)(ws + 55050240);  // [8192][768] bf16
  bf16_t* vt     = xb;                        // aliases xb: [4][12][64][2048] bf16

  prep_kernel<<<8448, 256, 0, stream>>>(x, xb, w_qkv, wqkvT, w_proj, wprojT);
  gemm_qkv_kernel<<<dim3(32, 18), 512, 0, stream>>>(xb, wqkvT, b_qkv, q, k, v);
  vtrans_kernel<<<dim3(32, 48), 256, 0, stream>>>(v, vt);
  attn_kernel<<<dim3(48, 16), 256, 0, stream>>>(q, k, vt, ao);
  gemm_proj_kernel<<<dim3(64, 6), 256, 0, stream>>>(ao, wprojT, b_proj, out);
}

// Round 16
// 203.526 us; speedup vs baseline: 1.0772x; 1.0448x over previous
//
#include <hip/hip_runtime.h>
#include <hip/hip_bf16.h>
#include <cstdint>

typedef __bf16 bf16_t;
typedef __bf16 bf16x4 __attribute__((ext_vector_type(4)));
typedef __bf16 bf16x8 __attribute__((ext_vector_type(8)));
typedef float floatx4 __attribute__((ext_vector_type(4)));
typedef float floatx16 __attribute__((ext_vector_type(16)));
typedef unsigned int u32x4 __attribute__((ext_vector_type(4)));

#define NB 4
#define NH 12
#define SEQ 2048
#define DM 768
#define LOG2E 1.44269504088896340736f

// async global->LDS, 16B per lane; LDS dest is wave-uniform base + lane*16
__device__ __forceinline__ void gload_lds16(const bf16_t* g, bf16_t* l) {
  auto gp = reinterpret_cast<const __attribute__((address_space(1))) uint32_t*>(
      reinterpret_cast<uintptr_t>(g));
  auto lp = reinterpret_cast<__attribute__((address_space(3))) uint32_t*>(
      reinterpret_cast<uintptr_t>(l));
  __builtin_amdgcn_global_load_lds(gp, lp, 16, 0, 0);
}

// pack two f32 -> one dword of 2 bf16 (lo = a, hi = b)
__device__ __forceinline__ unsigned int pack2(float a, float b) {
  bf16_t x = (bf16_t)a, y = (bf16_t)b;
  unsigned short ux = __builtin_bit_cast(unsigned short, x);
  unsigned short uy = __builtin_bit_cast(unsigned short, y);
  return (unsigned int)ux | ((unsigned int)uy << 16);
}

// ---------------------------------------------------------------- fused prep
__global__ __launch_bounds__(256) void prep_kernel(
    const float* __restrict__ x, bf16_t* __restrict__ xb,
    const float* __restrict__ wqkv, bf16_t* __restrict__ wqkvT,
    const float* __restrict__ wproj, bf16_t* __restrict__ wprojT) {
  const int bid = blockIdx.x;
  const int tid = threadIdx.x;
  if (bid < 6144) {
    int i = (bid * 256 + tid) * 4;
    float4 v = *(const float4*)(x + i);
    bf16x4 hh;
    hh[0] = (bf16_t)v.x; hh[1] = (bf16_t)v.y; hh[2] = (bf16_t)v.z; hh[3] = (bf16_t)v.w;
    *(bf16x4*)(xb + i) = hh;
    return;
  }
  const float* in;
  bf16_t* out;
  int N, nb, kb;
  if (bid < 7872) {
    int t = bid - 6144;
    in = wqkv; out = wqkvT; N = 2304;
    nb = (t % 72) * 32; kb = (t / 72) * 32;
  } else {
    int t = bid - 7872;
    in = wproj; out = wprojT; N = 768;
    nb = (t % 24) * 32; kb = (t / 24) * 32;
  }
  const int K = 768;
  __shared__ float tile[32][33];
  int tx = tid & 31, ty = tid >> 5;
#pragma unroll
  for (int r = ty; r < 32; r += 8)
    tile[r][tx] = in[(size_t)(kb + r) * N + nb + tx];
  __syncthreads();
#pragma unroll
  for (int r = ty; r < 32; r += 8)
    out[(size_t)(nb + r) * K + kb + tx] = (bf16_t)tile[tx][r];
}

// ---------------------------------------------------------------- QKV GEMM (m97 128², BK=32 — measured optimum; BK=64/256²/256x128 all regressed)
__global__ __launch_bounds__(256) void gemm_qkv_kernel(
    const bf16_t* __restrict__ A, const bf16_t* __restrict__ BT,
    const float* __restrict__ bias,
    bf16_t* __restrict__ Qo, bf16_t* __restrict__ Ko, bf16_t* __restrict__ Vo) {
  const int K = 768;
  __shared__ __align__(16) bf16_t As[128][32];
  __shared__ __align__(16) bf16_t Bs[128][32];
  const int m0 = blockIdx.x * 128, n0 = blockIdx.y * 128;
  const int tid = threadIdx.x;
  const int w = tid >> 6, lane = tid & 63, quad = lane >> 4, l16 = lane & 15;
  const int wm = w >> 1, wn = w & 1;
  const int ldrow = w * 32;
  const int grow = lane >> 2;
  const int gcol = (lane & 3) * 8;

  floatx4 acc[4][4];
#pragma unroll
  for (int mt = 0; mt < 4; mt++)
#pragma unroll
    for (int nt = 0; nt < 4; nt++) acc[mt][nt] = (floatx4)(0.f);

  const bf16_t* ga0 = A + (size_t)(m0 + ldrow) * K;
  const bf16_t* gb0 = BT + (size_t)(n0 + ldrow) * K;

  for (int k0 = 0; k0 < K; k0 += 32) {
    __syncthreads();
    gload_lds16(ga0 + (size_t)grow * K + k0 + gcol,        &As[ldrow][0]);
    gload_lds16(ga0 + (size_t)(grow + 16) * K + k0 + gcol, &As[ldrow + 16][0]);
    gload_lds16(gb0 + (size_t)grow * K + k0 + gcol,        &Bs[ldrow][0]);
    gload_lds16(gb0 + (size_t)(grow + 16) * K + k0 + gcol, &Bs[ldrow + 16][0]);
    __syncthreads();
    bf16x8 af[4], bfr[4];
#pragma unroll
    for (int mt = 0; mt < 4; mt++)
      af[mt] = *(const bf16x8*)&As[wm * 64 + mt * 16 + l16][quad * 8];
#pragma unroll
    for (int nt = 0; nt < 4; nt++)
      bfr[nt] = *(const bf16x8*)&Bs[wn * 64 + nt * 16 + l16][quad * 8];
#pragma unroll
    for (int mt = 0; mt < 4; mt++)
#pragma unroll
      for (int nt = 0; nt < 4; nt++)
        acc[mt][nt] = __builtin_amdgcn_mfma_f32_16x16x32_bf16(af[mt], bfr[nt], acc[mt][nt], 0, 0, 0);
  }

  const int which = n0 / 768;
  const int rem0 = n0 % 768;
  bf16_t* dst = which == 0 ? Qo : (which == 1 ? Ko : Vo);
  const float qscale = which == 0 ? (0.125f * LOG2E) : 1.0f;
#pragma unroll
  for (int nt = 0; nt < 4; nt++) {
    const int cc = wn * 64 + nt * 16 + l16;
    const int rem = rem0 + cc;
    const int h = rem >> 6, hd = rem & 63;
    const float bv = bias[n0 + cc];
#pragma unroll
    for (int mt = 0; mt < 4; mt++)
#pragma unroll
      for (int r = 0; r < 4; r++) {
        const int gr = m0 + wm * 64 + mt * 16 + quad * 4 + r;
        const int bb = gr >> 11, s = gr & 2047;
        const float val = (acc[mt][nt][r] + bv) * qscale;
        dst[((size_t)((bb * NH + h) * SEQ + s)) * 64 + hd] = (bf16_t)val;
      }
  }
}

// ---------------------------------------------------------------- V transpose
__global__ __launch_bounds__(256) void vtrans_kernel(const bf16_t* __restrict__ V,
                                                     bf16_t* __restrict__ Vt) {
  __shared__ bf16_t tile[64][66];
  int bh = blockIdx.y, s0 = blockIdx.x * 64;
  int tid = threadIdx.x;
  int r = tid >> 4, c4 = (tid & 15) * 4;
  const bf16_t* src = V + (size_t)bh * SEQ * 64;
#pragma unroll
  for (int rr = r; rr < 64; rr += 16)
    *(bf16x4*)&tile[rr][c4] = *(const bf16x4*)&src[(size_t)(s0 + rr) * 64 + c4];
  __syncthreads();
  bf16_t* dst = Vt + (size_t)bh * 64 * SEQ;
#pragma unroll
  for (int hd = r; hd < 64; hd += 16) {
    bf16x4 o;
    o[0] = tile[c4 + 0][hd]; o[1] = tile[c4 + 1][hd];
    o[2] = tile[c4 + 2][hd]; o[3] = tile[c4 + 3][hd];
    *(bf16x4*)&dst[(size_t)hd * SEQ + s0 + c4] = o;
  }
}

// ---------------------------------------------------------------- flash attention
// R9/R11 inner math (4 waves, grid (48,16), heaviest-first, triple-buffer LDS
// K/V, T13 defer-max, ones-MFMA l-sum). NEW SCHEDULE: prefetch depth 2 with
// stage-after-barrier — per iter: vmcnt(4) [covers loads issued 2 iters ago,
// wait ~0] -> s_barrier -> stage(kt+2) into buf[(kt+2)%3] -> compute(kt).
// Race-free: the barrier separates all waves' compute(kt-1) (reads
// buf[(kt-1)%3] == buf[(kt+2)%3]) from the stage into that buffer; each
// wave's vmcnt(4) before the barrier leaves only stage(kt+1) outstanding, so
// buf[kt] is globally landed after the barrier; barrier count wave-uniform.
__global__ __launch_bounds__(256, 3) void attn_kernel(
    const bf16_t* __restrict__ Q, const bf16_t* __restrict__ Kg,
    const bf16_t* __restrict__ Vt, bf16_t* __restrict__ Out) {
  __shared__ __align__(16) bf16_t Ks[3][64 * 64];
  __shared__ __align__(16) bf16_t Vs[3][64 * 64];
  const int tid = threadIdx.x;
  const int w = tid >> 6, lane = tid & 63;
  const int l31 = lane & 31, hi = lane >> 5;
  const int bh = blockIdx.x;
  const int b = bh / NH, h = bh % NH;
  const int qt = (int)(gridDim.y - 1) - (int)blockIdx.y;
  const int r0 = qt * 128 + w * 32;
  const int qrow = r0 + l31;
  const bf16_t* Qp = Q + (size_t)bh * SEQ * 64;
  const bf16_t* Kp = Kg + (size_t)bh * SEQ * 64;
  const bf16_t* Vp = Vt + (size_t)bh * 64 * SEQ;

  bf16x8 qf[4];
#pragma unroll
  for (int kc = 0; kc < 4; kc++)
    qf[kc] = *(const bf16x8*)&Qp[(size_t)qrow * 64 + kc * 16 + hi * 8];

  bf16x8 ones;
#pragma unroll
  for (int j = 0; j < 8; j++) ones[j] = (bf16_t)1.0f;

  float m_i = -1e30f;
  floatx16 accT[2];
  accT[0] = (floatx16)(0.f);
  accT[1] = (floatx16)(0.f);
  floatx16 zl = (floatx16)(0.f);

  const int nt_w = (r0 >> 6) + 1;
  const int ntmax = 2 * qt + 2;

  int srow[2], scolb[2];
#pragma unroll
  for (int r = 0; r < 2; r++) {
    int off = r * 4096 + w * 1024 + lane * 16;
    int row = off >> 7;
    srow[r] = row;
    scolb[r] = (off & 127) ^ ((row & 7) << 4);
  }

  auto stage = [&](int buf, int kt) {
    const int kbase = kt * 64;
#pragma unroll
    for (int r = 0; r < 2; r++) {
      gload_lds16(Kp + (size_t)(kbase + srow[r]) * 64 + (scolb[r] >> 1),
                  &Ks[buf][r * 2048 + w * 512]);
      gload_lds16(Vp + (size_t)srow[r] * SEQ + kbase + (scolb[r] >> 1),
                  &Vs[buf][r * 2048 + w * 512]);
    }
  };

  const int swz = (l31 & 7) << 4;

  // prologue: depth-2 prefetch
  stage(0, 0);
  if (ntmax > 1) stage(1, 1);

  for (int kt = 0; kt < ntmax; kt++) {
    const int cur = kt % 3;
    if (kt + 1 < ntmax) {
      asm volatile("s_waitcnt vmcnt(4)" ::: "memory");  // buf[kt] landed (issued 2 iters ago)
    } else {
      asm volatile("s_waitcnt vmcnt(0)" ::: "memory");
    }
    __builtin_amdgcn_s_barrier();  // everyone's buf[kt] visible; compute(kt-1) done
    if (kt + 2 < ntmax) {
      const int nb2 = (kt + 2) % 3;
      stage(nb2, kt + 2);  // safe: readers of this buf finished before the barrier
    }

    if (kt < nt_w) {
      const int kbase = kt * 64;
      const bf16_t* Kb = Ks[cur];
      const bf16_t* Vb = Vs[cur];
      floatx16 st[2];
#pragma unroll
      for (int kt2 = 0; kt2 < 2; kt2++) {
        const int row = kt2 * 32 + l31;
        floatx16 z = (floatx16)(0.f);
#pragma unroll
        for (int kc = 0; kc < 4; kc++) {
          bf16x8 kfr = *(const bf16x8*)&Kb[row * 64 + (((kc * 32 + hi * 16) ^ swz) >> 1)];
          z = __builtin_amdgcn_mfma_f32_32x32x16_bf16(kfr, qf[kc], z, 0, 0, 0);
        }
        st[kt2] = z;
      }
      if (kt == nt_w - 1) {
#pragma unroll
        for (int kt2 = 0; kt2 < 2; kt2++)
#pragma unroll
          for (int r = 0; r < 16; r++) {
            int key = kbase + kt2 * 32 + (r & 3) + 8 * (r >> 2) + 4 * hi;
            if (key > qrow) st[kt2][r] = -1e30f;
          }
      }
      float mloc = -1e30f;
#pragma unroll
      for (int kt2 = 0; kt2 < 2; kt2++)
#pragma unroll
        for (int r = 0; r < 16; r++) mloc = fmaxf(mloc, st[kt2][r]);
      mloc = fmaxf(mloc, __shfl_xor(mloc, 32));
      if (!__all((int)(mloc - m_i <= 8.f))) {
        const float mnew = fmaxf(m_i, mloc);
        const float al = __builtin_amdgcn_exp2f(m_i - mnew);
        m_i = mnew;
#pragma unroll
        for (int r = 0; r < 16; r++) zl[r] *= al;
#pragma unroll
        for (int dt = 0; dt < 2; dt++)
#pragma unroll
          for (int r = 0; r < 16; r++) accT[dt][r] *= al;
      }
#pragma unroll
      for (int kt2 = 0; kt2 < 2; kt2++)
#pragma unroll
        for (int r = 0; r < 16; r++)
          st[kt2][r] = __builtin_amdgcn_exp2f(st[kt2][r] - m_i);
#pragma unroll
      for (int kt2 = 0; kt2 < 2; kt2++) {
        unsigned int wds[8];
#pragma unroll
        for (int j = 0; j < 8; j++) wds[j] = pack2(st[kt2][2 * j], st[kt2][2 * j + 1]);
        unsigned int x0 = (unsigned int)__shfl_xor((int)(hi ? wds[0] : wds[2]), 32);
        unsigned int x1 = (unsigned int)__shfl_xor((int)(hi ? wds[1] : wds[3]), 32);
        unsigned int x2 = (unsigned int)__shfl_xor((int)(hi ? wds[4] : wds[6]), 32);
        unsigned int x3 = (unsigned int)__shfl_xor((int)(hi ? wds[5] : wds[7]), 32);
        u32x4 f0 = hi ? (u32x4){x0, x1, wds[2], wds[3]} : (u32x4){wds[0], wds[1], x0, x1};
        u32x4 f1 = hi ? (u32x4){x2, x3, wds[6], wds[7]} : (u32x4){wds[4], wds[5], x2, x3};
        bf16x8 pf0 = __builtin_bit_cast(bf16x8, f0);
        bf16x8 pf1 = __builtin_bit_cast(bf16x8, f1);
        zl = __builtin_amdgcn_mfma_f32_32x32x16_bf16(ones, pf0, zl, 0, 0, 0);
        zl = __builtin_amdgcn_mfma_f32_32x32x16_bf16(ones, pf1, zl, 0, 0, 0);
#pragma unroll
        for (int dt = 0; dt < 2; dt++) {
          const int vrow = dt * 32 + l31;
          bf16x8 v0 = *(const bf16x8*)&Vb[vrow * 64 + (((kt2 * 64 + hi * 16) ^ swz) >> 1)];
          bf16x8 v1 = *(const bf16x8*)&Vb[vrow * 64 + (((kt2 * 64 + 32 + hi * 16) ^ swz) >> 1)];
          accT[dt] = __builtin_amdgcn_mfma_f32_32x32x16_bf16(v0, pf0, accT[dt], 0, 0, 0);
          accT[dt] = __builtin_amdgcn_mfma_f32_32x32x16_bf16(v1, pf1, accT[dt], 0, 0, 0);
        }
      }
    }
  }

  const float inv_l = 1.0f / zl[0];
#pragma unroll
  for (int dt = 0; dt < 2; dt++)
#pragma unroll
    for (int g = 0; g < 4; g++) {
      bf16x4 o;
#pragma unroll
      for (int j = 0; j < 4; j++) o[j] = (bf16_t)(accT[dt][4 * g + j] * inv_l);
      int d = dt * 32 + 8 * g + 4 * hi;
      *(bf16x4*)&Out[((size_t)(b * SEQ + qrow)) * DM + h * 64 + d] = o;
    }
}

// ---------------------------------------------------------------- out-proj GEMM (m97 single-buffer, BK=32)
__global__ __launch_bounds__(256) void gemm_proj_kernel(
    const bf16_t* __restrict__ A, const bf16_t* __restrict__ BT,
    const float* __restrict__ bias, float* __restrict__ out) {
  const int K = 768;
  __shared__ __align__(16) bf16_t As[128][32];
  __shared__ __align__(16) bf16_t Bs[128][32];
  const int m0 = blockIdx.x * 128, n0 = blockIdx.y * 128;
  const int tid = threadIdx.x;
  const int w = tid >> 6, lane = tid & 63, quad = lane >> 4, l16 = lane & 15;
  const int wm = w >> 1, wn = w & 1;
  const int ldrow = w * 32;
  const int grow = lane >> 2;
  const int gcol = (lane & 3) * 8;

  floatx4 acc[4][4];
#pragma unroll
  for (int mt = 0; mt < 4; mt++)
#pragma unroll
    for (int nt = 0; nt < 4; nt++) acc[mt][nt] = (floatx4)(0.f);

  const bf16_t* ga0 = A + (size_t)(m0 + ldrow) * K;
  const bf16_t* gb0 = BT + (size_t)(n0 + ldrow) * K;

  for (int k0 = 0; k0 < K; k0 += 32) {
    __syncthreads();
    gload_lds16(ga0 + (size_t)grow * K + k0 + gcol,        &As[ldrow][0]);
    gload_lds16(ga0 + (size_t)(grow + 16) * K + k0 + gcol, &As[ldrow + 16][0]);
    gload_lds16(gb0 + (size_t)grow * K + k0 + gcol,        &Bs[ldrow][0]);
    gload_lds16(gb0 + (size_t)(grow + 16) * K + k0 + gcol, &Bs[ldrow + 16][0]);
    __syncthreads();
    bf16x8 af[4], bfr[4];
#pragma unroll
    for (int mt = 0; mt < 4; mt++)
      af[mt] = *(const bf16x8*)&As[wm * 64 + mt * 16 + l16][quad * 8];
#pragma unroll
    for (int nt = 0; nt < 4; nt++)
      bfr[nt] = *(const bf16x8*)&Bs[wn * 64 + nt * 16 + l16][quad * 8];
#pragma unroll
    for (int mt = 0; mt < 4; mt++)
#pragma unroll
      for (int nt = 0; nt < 4; nt++)
        acc[mt][nt] = __builtin_amdgcn_mfma_f32_16x16x32_bf16(af[mt], bfr[nt], acc[mt][nt], 0, 0, 0);
  }

#pragma unroll
  for (int nt = 0; nt < 4; nt++) {
    const int gc = n0 + wn * 64 + nt * 16 + l16;
    const float bv = bias[gc];
#pragma unroll
    for (int mt = 0; mt < 4; mt++)
#pragma unroll
      for (int r = 0; r < 4; r++) {
        const int gr = m0 + wm * 64 + mt * 16 + quad * 4 + r;
        out[(size_t)gr * 768 + gc] = acc[mt][nt][r] + bv;
      }
  }
}

// ---------------------------------------------------------------- launch
extern "C" void kernel_launch(void* const* d_in, const int* in_sizes, int n_in,
                              void* d_out, int out_size, void* d_ws, size_t ws_size,
                              hipStream_t stream) {
  const float* x      = (const float*)d_in[0];
  const float* w_qkv  = (const float*)d_in[1];
  const float* b_qkv  = (const float*)d_in[2];
  const float* w_proj = (const float*)d_in[3];
  const float* b_proj = (const float*)d_in[4];
  float* out = (float*)d_out;
  char* ws = (char*)d_ws;

  // workspace layout (all 16B-aligned), total 67,633,152 B
  bf16_t* xb     = (bf16_t*)(ws + 0);         // 8192*768  bf16 (dead after gemm_qkv)
  bf16_t* wqkvT  = (bf16_t*)(ws + 12582912);  // 2304*768  bf16
  bf16_t* wprojT = (bf16_t*)(ws + 16121856);  //  768*768  bf16
  bf16_t* q      = (bf16_t*)(ws + 17301504);  // [4][12][2048][64] bf16
  bf16_t* k      = (bf16_t*)(ws + 29884416);
  bf16_t* v      = (bf16_t*)(ws + 42467328);
  bf16_t* ao     = (bf16_t*)(ws + 55050240);  // [8192][768] bf16
  bf16_t* vt     = xb;                        // aliases xb: [4][12][64][2048] bf16

  prep_kernel<<<8448, 256, 0, stream>>>(x, xb, w_qkv, wqkvT, w_proj, wprojT);
  gemm_qkv_kernel<<<dim3(64, 18), 256, 0, stream>>>(xb, wqkvT, b_qkv, q, k, v);
  vtrans_kernel<<<dim3(32, 48), 256, 0, stream>>>(v, vt);
  attn_kernel<<<dim3(48, 16), 256, 0, stream>>>(q, k, vt, ao);
  gemm_proj_kernel<<<dim3(64, 6), 256, 0, stream>>>(ao, wprojT, b_proj, out);
}